// Round 9
// baseline (173.582 us; speedup 1.0000x reference)
//
#include <hip/hip_runtime.h>
#include <cstdint>
#include <cstddef>

typedef __attribute__((ext_vector_type(8))) short short8;
typedef __attribute__((ext_vector_type(8))) __bf16 bf16x8;
typedef __attribute__((ext_vector_type(4))) float f32x4;
typedef __attribute__((ext_vector_type(16))) float f32x16;
typedef __attribute__((ext_vector_type(4))) unsigned int uint32x4;

#define LOG2E 1.44269504088896340736f

__device__ __forceinline__ unsigned short f2bf(float f) {
    unsigned int u = __builtin_bit_cast(unsigned int, f);
    u += 0x7fffu + ((u >> 16) & 1u);
    return (unsigned short)(u >> 16);
}

__device__ __forceinline__ f32x4 zero4() {
    f32x4 z; z.x = 0.f; z.y = 0.f; z.z = 0.f; z.w = 0.f; return z;
}
__device__ __forceinline__ f32x16 zero16() {
    f32x16 z;
    #pragma unroll
    for (int i = 0; i < 16; ++i) z[i] = 0.f;
    return z;
}

__device__ __forceinline__ f32x4 mfma16(short8 a, short8 b, f32x4 c) {
    return __builtin_amdgcn_mfma_f32_16x16x32_bf16(
        __builtin_bit_cast(bf16x8, a), __builtin_bit_cast(bf16x8, b), c, 0, 0, 0);
}
__device__ __forceinline__ f32x16 mfma32(short8 a, short8 b, f32x16 c) {
    return __builtin_amdgcn_mfma_f32_32x32x16_bf16(
        __builtin_bit_cast(bf16x8, a), __builtin_bit_cast(bf16x8, b), c, 0, 0, 0);
}

__device__ __forceinline__ unsigned int cvt_pk_bf16(float lo, float hi) {
    unsigned int r;
    asm("v_cvt_pk_bf16_f32 %0, %1, %2" : "=v"(r) : "v"(lo), "v"(hi));
    return r;
}

// v_permlane32_swap_b32 (CDNA4 ISA): for l in 0..31: vdst[l+32] <-> vsrc[l].
// ret.x (new vdst): lanes<32 = x[l],    lanes>=32 = y[l-32]
// ret.y (new vsrc): lanes<32 = x[l+32], lanes>=32 = y[l]
__device__ __forceinline__ uint2 permswap(unsigned x, unsigned y) {
#if __has_builtin(__builtin_amdgcn_permlane32_swap)
    auto r = __builtin_amdgcn_permlane32_swap(x, y, false, false);
    return make_uint2(r[0], r[1]);
#else
    int lane = threadIdx.x & 63;
    unsigned sy = __shfl_xor(y, 32), sx = __shfl_xor(x, 32);
    return make_uint2((lane < 32) ? x : sy, (lane < 32) ? sx : y);
#endif
}
__device__ __forceinline__ float red_max32(float v) {
    unsigned u = __builtin_bit_cast(unsigned, v);
    uint2 p = permswap(u, u);
    return fmaxf(__builtin_bit_cast(float, p.x), __builtin_bit_cast(float, p.y));
}

// async 16B global->LDS: per-lane g, wave-uniform lds base l; HW writes l + lane*16
__device__ __forceinline__ void gload_lds16(const void* g, void* l, int lane) {
#if __has_builtin(__builtin_amdgcn_global_load_lds)
    __builtin_amdgcn_global_load_lds(
        (const __attribute__((address_space(1))) void*)g,
        (__attribute__((address_space(3))) void*)l, 16, 0, 0);
    (void)lane;
#else
    reinterpret_cast<int4*>(l)[lane] = *reinterpret_cast<const int4*>(g);
#endif
}

// ---------------- fused prep: 3x fp32->bf16 cast + RoPE table ----------------
__global__ __launch_bounds__(256) void prep_kernel(
    const float* __restrict__ x, const float* __restrict__ wq,
    const float* __restrict__ wo,
    unsigned short* __restrict__ xb, unsigned short* __restrict__ wqb,
    unsigned short* __restrict__ wob, float2* __restrict__ tab) {
    const int S0 = 1048576, S1 = 786432, S2 = 262144;   // float4 counts
    int i = blockIdx.x * 256 + threadIdx.x;
    const float* src; unsigned short* dst; int j;
    if (i < S0) { src = x; dst = xb; j = i; }
    else if (i < S0 + S1) { src = wq; dst = wqb; j = i - S0; }
    else if (i < S0 + S1 + S2) { src = wo; dst = wob; j = i - S0 - S1; }
    else {
        int idx = i - (S0 + S1 + S2);
        if (idx < 2048 * 32) {
            int t = idx >> 5, ii = idx & 31;
            float inv_freq = powf(10000.0f, -(float)ii / 32.0f);
            float ang = (float)t * inv_freq;
            tab[idx] = make_float2(cosf(ang), sinf(ang));
        }
        return;
    }
    float4 v = reinterpret_cast<const float4*>(src)[j];
    ushort4 o;
    o.x = f2bf(v.x); o.y = f2bf(v.y); o.z = f2bf(v.z); o.w = f2bf(v.w);
    reinterpret_cast<ushort4*>(dst)[j] = o;
}

// ---------------- shared 128x128 NT bf16 GEMM mainloop (BK=64), double-buffered ----------------
__device__ __forceinline__ void gemm_mainloop_128x128(
    const unsigned short* __restrict__ A, const unsigned short* __restrict__ B,
    int K, int m0, int n0, unsigned short* As, unsigned short* Bs, f32x4 acc[4][4]) {
    int tid = threadIdx.x;
    int wave = tid >> 6, lane = tid & 63;
    int wm = wave >> 1, wn = wave & 1;
    int g = lane >> 4, c = lane & 15;
    const int NS = K >> 6;

    auto stage = [&](int buf, int k0) {
        #pragma unroll
        for (int i = 0; i < 4; ++i) {
            int call = wave * 4 + i;
            int s = call * 64 + lane;
            int row = s >> 3, c8 = s & 7;
            int csw = (c8 ^ (row & 7)) << 3;
            gload_lds16(A + (size_t)(m0 + row) * K + k0 + csw,
                        (char*)As + buf * 16384 + call * 1024, lane);
            gload_lds16(B + (size_t)(n0 + row) * K + k0 + csw,
                        (char*)Bs + buf * 16384 + call * 1024, lane);
        }
    };

    stage(0, 0);   // tile 0 in flight

    #pragma unroll 1
    for (int t = 0; t < NS; ++t) {
        int cur = t & 1;
        asm volatile("s_waitcnt vmcnt(0) lgkmcnt(0)" ::: "memory");
        __builtin_amdgcn_s_barrier();    // all waves' tile-t resident; buf[cur^1] free
        __builtin_amdgcn_sched_barrier(0);
        if (t + 1 < NS) stage(cur ^ 1, (t + 1) * 64);   // in flight across compute

        const char* Ac = (const char*)As + cur * 16384;
        const char* Bc = (const char*)Bs + cur * 16384;
        #pragma unroll
        for (int kg = 0; kg < 2; ++kg) {
            short8 af[4], bfr[4];
            #pragma unroll
            for (int mt = 0; mt < 4; ++mt) {
                int row = wm * 64 + mt * 16 + c;
                af[mt] = *reinterpret_cast<const short8*>(Ac +
                    ((row * 128 + kg * 64 + g * 16) ^ ((row & 7) << 4)));
            }
            #pragma unroll
            for (int nt = 0; nt < 4; ++nt) {
                int row = wn * 64 + nt * 16 + c;
                bfr[nt] = *reinterpret_cast<const short8*>(Bc +
                    ((row * 128 + kg * 64 + g * 16) ^ ((row & 7) << 4)));
            }
            __builtin_amdgcn_s_setprio(1);
            #pragma unroll
            for (int mt = 0; mt < 4; ++mt)
                #pragma unroll
                for (int nt = 0; nt < 4; ++nt)
                    acc[mt][nt] = mfma16(af[mt], bfr[nt], acc[mt][nt]);
            __builtin_amdgcn_s_setprio(0);
        }
    }
}

// ---------------- QKV GEMM + bias + RoPE; q (pre-scaled by 0.125*log2e), k -> [B*H][T][64], v -> [B*H][64][T] ----------------
__global__ __launch_bounds__(256) void qkv_gemm_kernel(
    const unsigned short* __restrict__ X, const unsigned short* __restrict__ W,
    const float* __restrict__ bias, const float2* __restrict__ tab,
    unsigned short* __restrict__ q, unsigned short* __restrict__ k,
    unsigned short* __restrict__ vt) {
    __shared__ unsigned short As[2][128 * 64];
    __shared__ unsigned short Bs[2][128 * 64];
    const int K = 1024;
    const float SCL = 0.125f * LOG2E;   // folded into q
    int flat = blockIdx.x + 24 * blockIdx.y;
    int swzb = (flat & 7) * 96 + (flat >> 3);
    int m0 = (swzb / 24) * 128, n0 = (swzb % 24) * 128;
    f32x4 acc[4][4];
    #pragma unroll
    for (int i = 0; i < 4; ++i)
        #pragma unroll
        for (int j = 0; j < 4; ++j) acc[i][j] = zero4();

    gemm_mainloop_128x128(X, W, K, m0, n0, &As[0][0], &Bs[0][0], acc);

    int tid = threadIdx.x;
    int wave = tid >> 6, lane = tid & 63;
    int wm = wave >> 1, wn = wave & 1;
    int g = lane >> 4, c = lane & 15;
    int mbase = m0 + wm * 64, nbase = n0 + wn * 64;
    #pragma unroll
    for (int mt = 0; mt < 4; ++mt) {
        #pragma unroll
        for (int nt = 0; nt < 4; ++nt) {
            f32x4 a = acc[mt][nt];
            int n = nbase + nt * 16 + c;
            int s = n >> 10;            // 0=q 1=k 2=v
            int h = (n >> 6) & 15;
            int d = n & 63;
            float bn = bias[n];
            #pragma unroll
            for (int r = 0; r < 4; ++r) {
                int m = mbase + mt * 16 + g * 4 + r;
                int bb = m >> 11, t = m & 2047;
                float val = a[r] + bn;
                float partner = __shfl_xor(val, 1);
                int bh = bb * 16 + h;
                if (s == 2) {
                    vt[((size_t)bh * 64 + d) * 2048 + t] = f2bf(val);
                } else {
                    int i2 = d >> 1;
                    float2 cs = tab[t * 32 + i2];
                    float outv; int dout;
                    if ((d & 1) == 0) { outv = val * cs.x - partner * cs.y; dout = i2; }
                    else              { outv = partner * cs.y + val * cs.x; dout = 32 + i2; }
                    if (s == 0) outv *= SCL;
                    (s == 0 ? q : k)[((size_t)bh * 2048 + t) * 64 + dout] = f2bf(outv);
                }
            }
        }
    }
}

// ---------------- flash attention: swapped-operand 32x32, SPLIT-KV 8-wave blocks ----------------
// Waves 0-3: j in [0,1024); waves 4-7: j in [1024,2048) for the SAME 128 q-rows.
// Each wave-pair (w, w+4) covers q rows pair*32..pair*32+31 with private (m,l,O);
// end merge via LDS (identical register layouts -> direct lane-wise exchange).
// 2 blocks/CU x 8 waves = 16 waves/CU (2x TLP vs round 8's latency-bound 8).
// l accumulated via ones-MFMA (lacc) instead of a 31-op VALU add tree.
__global__ __launch_bounds__(512, 4) void attn_kernel(
    const unsigned short* __restrict__ Q, const unsigned short* __restrict__ Kin,
    const unsigned short* __restrict__ VT, unsigned short* __restrict__ O) {
    __shared__ int4 smem4[65536 / 16];     // 64 KB
    char* smem = (char*)smem4;
    const int T = 2048, NT = 16;           // 16 tiles of 64 j per half
    int flat = blockIdx.x + 16 * blockIdx.y;
    int swzb = (flat & 7) * 64 + (flat >> 3);
    int bh = swzb >> 4;
    int qt = swzb & 15;
    int tid = threadIdx.x, wave = tid >> 6, lane = tid & 63;
    int lam = lane & 31, hi = lane >> 5;
    int pair = wave & 3, half = wave >> 2;
    int q = qt * 128 + pair * 32 + lam;

    const unsigned short* Qb = Q + ((size_t)bh * T + q) * 64;
    const unsigned short* Kb = Kin + (size_t)bh * T * 64;
    const unsigned short* VTb = VT + (size_t)bh * 64 * T;

    // Q fragments: load + pin in prologue (keeps the loads out of the loop).
    uint32x4 qtmp[4];
    #pragma unroll
    for (int c4 = 0; c4 < 4; ++c4)
        qtmp[c4] = *reinterpret_cast<const uint32x4*>(Qb + c4 * 16 + hi * 8);
    #pragma unroll
    for (int c4 = 0; c4 < 4; ++c4)
        asm volatile("" : "+v"(qtmp[c4]));
    short8 qf[4];
    #pragma unroll
    for (int c4 = 0; c4 < 4; ++c4) qf[c4] = __builtin_bit_cast(short8, qtmp[c4]);

    short8 ones;
    #pragma unroll
    for (int i = 0; i < 8; ++i) ones[i] = (short)0x3F80;   // bf16 1.0

    f32x16 o0 = zero16(), o1 = zero16(), lacc = zero16();
    float m_run = -1e30f;
    int swz = (lam & 7) << 4;

    // this half's LDS: [buf0|buf1] 8KB each
    char* Ks0 = smem + half * 16384;
    char* Vs0 = smem + 32768 + half * 16384;

    // staging: 4 waves of a half fill its 8KB K-tile + 8KB V-tile (4 loads/wave)
    auto stage = [&](int buf, int t) {
        int j0 = half * 1024 + t * 64;
        #pragma unroll
        for (int i = 0; i < 2; ++i) {
            int call = pair * 2 + i;           // 0..7
            int s = call * 64 + lane;
            int row = s >> 3, c8 = s & 7;
            int csw = (c8 ^ (row & 7)) << 3;
            gload_lds16(Kb + (size_t)(j0 + row) * 64 + csw,
                        Ks0 + buf * 8192 + call * 1024, lane);
            gload_lds16(VTb + (size_t)row * T + j0 + csw,
                        Vs0 + buf * 8192 + call * 1024, lane);
        }
    };

    stage(0, 0);     // prologue: tile 0 in flight

    #pragma unroll 1
    for (int t = 0; t < NT; ++t) {
        int cur = t & 1;
        // my tile-t loads done (one full compute phase in flight); my ds_reads drained
        asm volatile("s_waitcnt vmcnt(0) lgkmcnt(0)" ::: "memory");
        __builtin_amdgcn_s_barrier();
        __builtin_amdgcn_sched_barrier(0);
        if (t + 1 < NT) stage(cur ^ 1, t + 1);   // in flight across compute

        const char* Kc = Ks0 + cur * 8192;
        const char* Vc = Vs0 + cur * 8192;

        // ---- S^T = K Q^T over d-chunks of 16 ----
        f32x16 s0 = zero16(), s1 = zero16();
        __builtin_amdgcn_s_setprio(1);
        #pragma unroll
        for (int c4 = 0; c4 < 4; ++c4) {
            int col = c4 * 32 + hi * 16;
            short8 kf0 = *reinterpret_cast<const short8*>(Kc + ((lam * 128 + col) ^ swz));
            s0 = mfma32(kf0, qf[c4], s0);
            short8 kf1 = *reinterpret_cast<const short8*>(Kc + (((lam + 32) * 128 + col) ^ swz));
            s1 = mfma32(kf1, qf[c4], s1);
        }
        __builtin_amdgcn_s_setprio(0);

        // ---- online softmax (scale pre-folded into q); max3-fusable chain; defer THR=8 ----
        float tm = fmaxf(s0[0], s1[0]);
        #pragma unroll
        for (int r = 1; r < 16; ++r) tm = fmaxf(tm, fmaxf(s0[r], s1[r]));
        float tmax = red_max32(tm);
        if (__any(tmax - m_run > 8.0f)) {
            float mnew = fmaxf(m_run, tmax);
            float alpha = exp2f(m_run - mnew);
            m_run = mnew;
            #pragma unroll
            for (int r = 0; r < 16; ++r) {
                o0[r] *= alpha; o1[r] *= alpha; lacc[r] *= alpha;
            }
        }
        float p0[16], p1[16];
        #pragma unroll
        for (int r = 0; r < 16; ++r) p0[r] = exp2f(s0[r] - m_run);
        #pragma unroll
        for (int r = 0; r < 16; ++r) p1[r] = exp2f(s1[r] - m_run);

        // ---- P -> bf16 A-frags: cvt_pk + permlane32_swap cross-half exchange ----
        short8 pa[4];
        #pragma unroll
        for (int blk = 0; blk < 2; ++blk) {
            const float* p = blk ? p1 : p0;
            #pragma unroll
            for (int jt = 0; jt < 2; ++jt) {
                unsigned a0 = cvt_pk_bf16(p[jt * 8 + 0], p[jt * 8 + 1]);
                unsigned a1 = cvt_pk_bf16(p[jt * 8 + 2], p[jt * 8 + 3]);
                unsigned b0 = cvt_pk_bf16(p[jt * 8 + 4], p[jt * 8 + 5]);
                unsigned b1 = cvt_pk_bf16(p[jt * 8 + 6], p[jt * 8 + 7]);
                uint2 pr0 = permswap(a0, b0);
                uint2 pr1 = permswap(a1, b1);
                uint4 w;
                w.x = pr0.x;
                w.y = pr1.x;
                w.z = pr0.y;
                w.w = pr1.y;
                pa[blk * 2 + jt] = __builtin_bit_cast(short8, w);
            }
        }

        // ---- O^T += V^T P (+ l via ones-MFMA): d on reg-rows, q on lanes ----
        __builtin_amdgcn_s_setprio(1);
        #pragma unroll
        for (int jt = 0; jt < 4; ++jt) {
            int col = jt * 32 + hi * 16;
            short8 vf0 = *reinterpret_cast<const short8*>(Vc + ((lam * 128 + col) ^ swz));
            o0 = mfma32(vf0, pa[jt], o0);
            short8 vf1 = *reinterpret_cast<const short8*>(Vc + (((lam + 32) * 128 + col) ^ swz));
            o1 = mfma32(vf1, pa[jt], o1);
            lacc = mfma32(ones, pa[jt], lacc);
        }
        __builtin_amdgcn_s_setprio(0);
    }

    float l_run = lacc[0];

    // ---- split-KV merge: upper-half waves publish (o, m, l); lower-half merges ----
    __syncthreads();
    float* pb = (float*)(smem + pair * 8704);   // [64 lanes][34 f32]
    if (half) {
        #pragma unroll
        for (int r = 0; r < 16; ++r) {
            pb[lane * 34 + r] = o0[r];
            pb[lane * 34 + 16 + r] = o1[r];
        }
        pb[lane * 34 + 32] = m_run;
        pb[lane * 34 + 33] = l_run;
    }
    __syncthreads();
    if (half) return;

    float mb = pb[lane * 34 + 32], lb = pb[lane * 34 + 33];
    float m = fmaxf(m_run, mb);
    float wa = exp2f(m_run - m), wb = exp2f(mb - m);
    float l = l_run * wa + lb * wb;
    float rinv = 1.0f / l;
    #pragma unroll
    for (int r = 0; r < 16; ++r) {
        o0[r] = o0[r] * wa + pb[lane * 34 + r] * wb;
        o1[r] = o1[r] * wa + pb[lane * 34 + 16 + r] * wb;
    }

    // ---- epilogue: O[q][d] = o[d-reg][q] / l ; write [B][T][H*64] ----
    int b_ = bh >> 4, h_ = bh & 15;
    unsigned short* Orow = O + ((size_t)(b_ * 2048) + q) * 1024 + h_ * 64;
    #pragma unroll
    for (int rq = 0; rq < 4; ++rq) {
        ushort4 w0, w1;
        w0.x = f2bf(o0[rq * 4 + 0] * rinv);
        w0.y = f2bf(o0[rq * 4 + 1] * rinv);
        w0.z = f2bf(o0[rq * 4 + 2] * rinv);
        w0.w = f2bf(o0[rq * 4 + 3] * rinv);
        w1.x = f2bf(o1[rq * 4 + 0] * rinv);
        w1.y = f2bf(o1[rq * 4 + 1] * rinv);
        w1.z = f2bf(o1[rq * 4 + 2] * rinv);
        w1.w = f2bf(o1[rq * 4 + 3] * rinv);
        int d0 = rq * 8 + hi * 4;
        *reinterpret_cast<ushort4*>(Orow + d0) = w0;
        *reinterpret_cast<ushort4*>(Orow + 32 + d0) = w1;
    }
}

// ---------------- output GEMM + bias, fp32 out ----------------
__global__ __launch_bounds__(256) void out_gemm_kernel(
    const unsigned short* __restrict__ Aattn, const unsigned short* __restrict__ W,
    const float* __restrict__ bias, float* __restrict__ out) {
    __shared__ unsigned short As[2][128 * 64];
    __shared__ unsigned short Bs[2][128 * 64];
    const int K = 1024, N = 1024;
    int flat = blockIdx.x + 8 * blockIdx.y;
    int swzb = (flat & 7) * 32 + (flat >> 3);
    int m0 = (swzb >> 3) * 128, n0 = (swzb & 7) * 128;
    f32x4 acc[4][4];
    #pragma unroll
    for (int i = 0; i < 4; ++i)
        #pragma unroll
        for (int j = 0; j < 4; ++j) acc[i][j] = zero4();

    gemm_mainloop_128x128(Aattn, W, K, m0, n0, &As[0][0], &Bs[0][0], acc);

    int tid = threadIdx.x;
    int wave = tid >> 6, lane = tid & 63;
    int wm = wave >> 1, wn = wave & 1;
    int g = lane >> 4, c = lane & 15;
    int mbase = m0 + wm * 64, nbase = n0 + wn * 64;
    #pragma unroll
    for (int mt = 0; mt < 4; ++mt)
        #pragma unroll
        for (int nt = 0; nt < 4; ++nt) {
            int n = nbase + nt * 16 + c;
            float bn = bias[n];
            #pragma unroll
            for (int r = 0; r < 4; ++r) {
                int m = mbase + mt * 16 + g * 4 + r;
                out[(size_t)m * N + n] = acc[mt][nt][r] + bn;
            }
        }
}

extern "C" void kernel_launch(void* const* d_in, const int* in_sizes, int n_in,
                              void* d_out, int out_size, void* d_ws, size_t ws_size,
                              hipStream_t stream) {
    (void)in_sizes; (void)n_in; (void)out_size; (void)ws_size;
    const float* x     = (const float*)d_in[0];
    const float* w_qkv = (const float*)d_in[1];
    const float* b_qkv = (const float*)d_in[2];
    const float* w_out = (const float*)d_in[3];
    const float* b_out = (const float*)d_in[4];
    float* out = (float*)d_out;

    const int B = 2, T = 2048, D = 1024;
    const int M = B * T;                 // 4096
    const size_t MB = 1024 * 1024;

    char* ws = (char*)d_ws;
    unsigned short* xb    = (unsigned short*)(ws);            // 8 MB  x bf16 [4096][1024]
    unsigned short* wqkvb = (unsigned short*)(ws + 8 * MB);   // 6 MB  w_qkv bf16
    unsigned short* woutb = (unsigned short*)(ws + 14 * MB);  // 2 MB  w_out bf16
    unsigned short* qb    = (unsigned short*)(ws + 16 * MB);  // 8 MB  q (pre-scaled) [32][2048][64]
    unsigned short* kb    = (unsigned short*)(ws + 24 * MB);  // 8 MB  k
    unsigned short* vtb   = (unsigned short*)(ws + 32 * MB);  // 8 MB  v^T [32][64][2048]
    unsigned short* attnb = (unsigned short*)(ws + 40 * MB);  // 8 MB  attn out [4096][1024]
    float2* tab           = (float2*)(ws + 48 * MB);          // 512 KB rope table

    prep_kernel<<<dim3((2097152 + 65536) / 256), dim3(256), 0, stream>>>(
        x, w_qkv, w_out, xb, wqkvb, woutb, tab);
    qkv_gemm_kernel<<<dim3(3 * D / 128, M / 128), dim3(256), 0, stream>>>(xb, wqkvb, b_qkv, tab, qb, kb, vtb);
    attn_kernel<<<dim3(T / 128, B * 16), dim3(512), 0, stream>>>(qb, kb, vtb, attnb);
    out_gemm_kernel<<<dim3(D / 128, M / 128), dim3(256), 0, stream>>>(attnb, woutb, b_out, out);
}

// Round 10
// 166.365 us; speedup vs baseline: 1.0434x; 1.0434x over previous
//
#include <hip/hip_runtime.h>
#include <cstdint>
#include <cstddef>

typedef __attribute__((ext_vector_type(8))) short short8;
typedef __attribute__((ext_vector_type(8))) __bf16 bf16x8;
typedef __attribute__((ext_vector_type(4))) float f32x4;
typedef __attribute__((ext_vector_type(16))) float f32x16;
typedef __attribute__((ext_vector_type(4))) unsigned int uint32x4;

#define LOG2E 1.44269504088896340736f

__device__ __forceinline__ unsigned short f2bf(float f) {
    unsigned int u = __builtin_bit_cast(unsigned int, f);
    u += 0x7fffu + ((u >> 16) & 1u);
    return (unsigned short)(u >> 16);
}

__device__ __forceinline__ f32x4 zero4() {
    f32x4 z; z.x = 0.f; z.y = 0.f; z.z = 0.f; z.w = 0.f; return z;
}
__device__ __forceinline__ f32x16 zero16() {
    f32x16 z;
    #pragma unroll
    for (int i = 0; i < 16; ++i) z[i] = 0.f;
    return z;
}

__device__ __forceinline__ f32x4 mfma16(short8 a, short8 b, f32x4 c) {
    return __builtin_amdgcn_mfma_f32_16x16x32_bf16(
        __builtin_bit_cast(bf16x8, a), __builtin_bit_cast(bf16x8, b), c, 0, 0, 0);
}
__device__ __forceinline__ f32x16 mfma32(short8 a, short8 b, f32x16 c) {
    return __builtin_amdgcn_mfma_f32_32x32x16_bf16(
        __builtin_bit_cast(bf16x8, a), __builtin_bit_cast(bf16x8, b), c, 0, 0, 0);
}

__device__ __forceinline__ unsigned int cvt_pk_bf16(float lo, float hi) {
    unsigned int r;
    asm("v_cvt_pk_bf16_f32 %0, %1, %2" : "=v"(r) : "v"(lo), "v"(hi));
    return r;
}

// v_permlane32_swap_b32 (CDNA4 ISA): for l in 0..31: vdst[l+32] <-> vsrc[l].
// ret.x (new vdst): lanes<32 = x[l],    lanes>=32 = y[l-32]
// ret.y (new vsrc): lanes<32 = x[l+32], lanes>=32 = y[l]
__device__ __forceinline__ uint2 permswap(unsigned x, unsigned y) {
#if __has_builtin(__builtin_amdgcn_permlane32_swap)
    auto r = __builtin_amdgcn_permlane32_swap(x, y, false, false);
    return make_uint2(r[0], r[1]);
#else
    int lane = threadIdx.x & 63;
    unsigned sy = __shfl_xor(y, 32), sx = __shfl_xor(x, 32);
    return make_uint2((lane < 32) ? x : sy, (lane < 32) ? sx : y);
#endif
}
__device__ __forceinline__ float red_max32(float v) {
    unsigned u = __builtin_bit_cast(unsigned, v);
    uint2 p = permswap(u, u);
    return fmaxf(__builtin_bit_cast(float, p.x), __builtin_bit_cast(float, p.y));
}

// async 16B global->LDS: per-lane g, wave-uniform lds base l; HW writes l + lane*16
__device__ __forceinline__ void gload_lds16(const void* g, void* l, int lane) {
#if __has_builtin(__builtin_amdgcn_global_load_lds)
    __builtin_amdgcn_global_load_lds(
        (const __attribute__((address_space(1))) void*)g,
        (__attribute__((address_space(3))) void*)l, 16, 0, 0);
    (void)lane;
#else
    reinterpret_cast<int4*>(l)[lane] = *reinterpret_cast<const int4*>(g);
#endif
}

// ---------------- fused prep: 3x fp32->bf16 cast + RoPE table ----------------
__global__ __launch_bounds__(256) void prep_kernel(
    const float* __restrict__ x, const float* __restrict__ wq,
    const float* __restrict__ wo,
    unsigned short* __restrict__ xb, unsigned short* __restrict__ wqb,
    unsigned short* __restrict__ wob, float2* __restrict__ tab) {
    const int S0 = 1048576, S1 = 786432, S2 = 262144;   // float4 counts
    int i = blockIdx.x * 256 + threadIdx.x;
    const float* src; unsigned short* dst; int j;
    if (i < S0) { src = x; dst = xb; j = i; }
    else if (i < S0 + S1) { src = wq; dst = wqb; j = i - S0; }
    else if (i < S0 + S1 + S2) { src = wo; dst = wob; j = i - S0 - S1; }
    else {
        int idx = i - (S0 + S1 + S2);
        if (idx < 2048 * 32) {
            int t = idx >> 5, ii = idx & 31;
            float inv_freq = powf(10000.0f, -(float)ii / 32.0f);
            float ang = (float)t * inv_freq;
            tab[idx] = make_float2(cosf(ang), sinf(ang));
        }
        return;
    }
    float4 v = reinterpret_cast<const float4*>(src)[j];
    ushort4 o;
    o.x = f2bf(v.x); o.y = f2bf(v.y); o.z = f2bf(v.z); o.w = f2bf(v.w);
    reinterpret_cast<ushort4*>(dst)[j] = o;
}

// ---------------- shared 128x128 NT bf16 GEMM mainloop (BK=64), double-buffered ----------------
__device__ __forceinline__ void gemm_mainloop_128x128(
    const unsigned short* __restrict__ A, const unsigned short* __restrict__ B,
    int K, int m0, int n0, unsigned short* As, unsigned short* Bs, f32x4 acc[4][4]) {
    int tid = threadIdx.x;
    int wave = tid >> 6, lane = tid & 63;
    int wm = wave >> 1, wn = wave & 1;
    int g = lane >> 4, c = lane & 15;
    const int NS = K >> 6;

    auto stage = [&](int buf, int k0) {
        #pragma unroll
        for (int i = 0; i < 4; ++i) {
            int call = wave * 4 + i;
            int s = call * 64 + lane;
            int row = s >> 3, c8 = s & 7;
            int csw = (c8 ^ (row & 7)) << 3;
            gload_lds16(A + (size_t)(m0 + row) * K + k0 + csw,
                        (char*)As + buf * 16384 + call * 1024, lane);
            gload_lds16(B + (size_t)(n0 + row) * K + k0 + csw,
                        (char*)Bs + buf * 16384 + call * 1024, lane);
        }
    };

    stage(0, 0);   // tile 0 in flight

    #pragma unroll 1
    for (int t = 0; t < NS; ++t) {
        int cur = t & 1;
        asm volatile("s_waitcnt vmcnt(0) lgkmcnt(0)" ::: "memory");
        __builtin_amdgcn_s_barrier();    // all waves' tile-t resident; buf[cur^1] free
        __builtin_amdgcn_sched_barrier(0);
        if (t + 1 < NS) stage(cur ^ 1, (t + 1) * 64);   // in flight across compute

        const char* Ac = (const char*)As + cur * 16384;
        const char* Bc = (const char*)Bs + cur * 16384;
        #pragma unroll
        for (int kg = 0; kg < 2; ++kg) {
            short8 af[4], bfr[4];
            #pragma unroll
            for (int mt = 0; mt < 4; ++mt) {
                int row = wm * 64 + mt * 16 + c;
                af[mt] = *reinterpret_cast<const short8*>(Ac +
                    ((row * 128 + kg * 64 + g * 16) ^ ((row & 7) << 4)));
            }
            #pragma unroll
            for (int nt = 0; nt < 4; ++nt) {
                int row = wn * 64 + nt * 16 + c;
                bfr[nt] = *reinterpret_cast<const short8*>(Bc +
                    ((row * 128 + kg * 64 + g * 16) ^ ((row & 7) << 4)));
            }
            __builtin_amdgcn_s_setprio(1);
            #pragma unroll
            for (int mt = 0; mt < 4; ++mt)
                #pragma unroll
                for (int nt = 0; nt < 4; ++nt)
                    acc[mt][nt] = mfma16(af[mt], bfr[nt], acc[mt][nt]);
            __builtin_amdgcn_s_setprio(0);
        }
    }
}

// ---------------- QKV GEMM + bias + RoPE; q (pre-scaled by 0.125*log2e), k -> [B*H][T][64], v -> [B*H][64][T] ----------------
__global__ __launch_bounds__(256) void qkv_gemm_kernel(
    const unsigned short* __restrict__ X, const unsigned short* __restrict__ W,
    const float* __restrict__ bias, const float2* __restrict__ tab,
    unsigned short* __restrict__ q, unsigned short* __restrict__ k,
    unsigned short* __restrict__ vt) {
    __shared__ unsigned short As[2][128 * 64];
    __shared__ unsigned short Bs[2][128 * 64];
    const int K = 1024;
    const float SCL = 0.125f * LOG2E;   // folded into q
    int flat = blockIdx.x + 24 * blockIdx.y;
    int swzb = (flat & 7) * 96 + (flat >> 3);
    int m0 = (swzb / 24) * 128, n0 = (swzb % 24) * 128;
    f32x4 acc[4][4];
    #pragma unroll
    for (int i = 0; i < 4; ++i)
        #pragma unroll
        for (int j = 0; j < 4; ++j) acc[i][j] = zero4();

    gemm_mainloop_128x128(X, W, K, m0, n0, &As[0][0], &Bs[0][0], acc);

    int tid = threadIdx.x;
    int wave = tid >> 6, lane = tid & 63;
    int wm = wave >> 1, wn = wave & 1;
    int g = lane >> 4, c = lane & 15;
    int mbase = m0 + wm * 64, nbase = n0 + wn * 64;
    #pragma unroll
    for (int mt = 0; mt < 4; ++mt) {
        #pragma unroll
        for (int nt = 0; nt < 4; ++nt) {
            f32x4 a = acc[mt][nt];
            int n = nbase + nt * 16 + c;
            int s = n >> 10;            // 0=q 1=k 2=v
            int h = (n >> 6) & 15;
            int d = n & 63;
            float bn = bias[n];
            #pragma unroll
            for (int r = 0; r < 4; ++r) {
                int m = mbase + mt * 16 + g * 4 + r;
                int bb = m >> 11, t = m & 2047;
                float val = a[r] + bn;
                float partner = __shfl_xor(val, 1);
                int bh = bb * 16 + h;
                if (s == 2) {
                    vt[((size_t)bh * 64 + d) * 2048 + t] = f2bf(val);
                } else {
                    int i2 = d >> 1;
                    float2 cs = tab[t * 32 + i2];
                    float outv; int dout;
                    if ((d & 1) == 0) { outv = val * cs.x - partner * cs.y; dout = i2; }
                    else              { outv = partner * cs.y + val * cs.x; dout = 32 + i2; }
                    if (s == 0) outv *= SCL;
                    (s == 0 ? q : k)[((size_t)bh * 2048 + t) * 64 + dout] = f2bf(outv);
                }
            }
        }
    }
}

// ---------------- flash attention: swapped-operand 32x32, SPLIT-KV 8-wave blocks ----------------
// Waves 0-3: j in [0,1024); waves 4-7: j in [1024,2048) for the SAME 128 q-rows.
// __launch_bounds__(512, 2): 256-VGPR budget (round 9's (512,4) forced a 128-reg
// cap -> accumulators spilled to scratch: VGPR_Count 64, +19MB HBM writes).
// Occupancy is LDS-capped at 2 blocks/CU (2x64KB) = 16 waves/CU either way.
__global__ __launch_bounds__(512, 2) void attn_kernel(
    const unsigned short* __restrict__ Q, const unsigned short* __restrict__ Kin,
    const unsigned short* __restrict__ VT, unsigned short* __restrict__ O) {
    __shared__ int4 smem4[65536 / 16];     // 64 KB
    char* smem = (char*)smem4;
    const int T = 2048, NT = 16;           // 16 tiles of 64 j per half
    int flat = blockIdx.x + 16 * blockIdx.y;
    int swzb = (flat & 7) * 64 + (flat >> 3);
    int bh = swzb >> 4;
    int qt = swzb & 15;
    int tid = threadIdx.x, wave = tid >> 6, lane = tid & 63;
    int lam = lane & 31, hi = lane >> 5;
    int pair = wave & 3, half = wave >> 2;
    int q = qt * 128 + pair * 32 + lam;

    const unsigned short* Qb = Q + ((size_t)bh * T + q) * 64;
    const unsigned short* Kb = Kin + (size_t)bh * T * 64;
    const unsigned short* VTb = VT + (size_t)bh * 64 * T;

    // Q fragments: load + pin in prologue (keeps the loads out of the loop).
    uint32x4 qtmp[4];
    #pragma unroll
    for (int c4 = 0; c4 < 4; ++c4)
        qtmp[c4] = *reinterpret_cast<const uint32x4*>(Qb + c4 * 16 + hi * 8);
    #pragma unroll
    for (int c4 = 0; c4 < 4; ++c4)
        asm volatile("" : "+v"(qtmp[c4]));
    short8 qf[4];
    #pragma unroll
    for (int c4 = 0; c4 < 4; ++c4) qf[c4] = __builtin_bit_cast(short8, qtmp[c4]);

    short8 ones;
    #pragma unroll
    for (int i = 0; i < 8; ++i) ones[i] = (short)0x3F80;   // bf16 1.0

    f32x16 o0 = zero16(), o1 = zero16(), lacc = zero16();
    float m_run = -1e30f;
    int swz = (lam & 7) << 4;

    // this half's LDS: [buf0|buf1] 8KB each
    char* Ks0 = smem + half * 16384;
    char* Vs0 = smem + 32768 + half * 16384;

    // staging: 4 waves of a half fill its 8KB K-tile + 8KB V-tile (4 loads/wave)
    auto stage = [&](int buf, int t) {
        int j0 = half * 1024 + t * 64;
        #pragma unroll
        for (int i = 0; i < 2; ++i) {
            int call = pair * 2 + i;           // 0..7
            int s = call * 64 + lane;
            int row = s >> 3, c8 = s & 7;
            int csw = (c8 ^ (row & 7)) << 3;
            gload_lds16(Kb + (size_t)(j0 + row) * 64 + csw,
                        Ks0 + buf * 8192 + call * 1024, lane);
            gload_lds16(VTb + (size_t)row * T + j0 + csw,
                        Vs0 + buf * 8192 + call * 1024, lane);
        }
    };

    stage(0, 0);     // prologue: tile 0 in flight

    #pragma unroll 1
    for (int t = 0; t < NT; ++t) {
        int cur = t & 1;
        // my tile-t loads done (one full compute phase in flight); my ds_reads drained
        asm volatile("s_waitcnt vmcnt(0) lgkmcnt(0)" ::: "memory");
        __builtin_amdgcn_s_barrier();
        __builtin_amdgcn_sched_barrier(0);
        if (t + 1 < NT) stage(cur ^ 1, t + 1);   // in flight across compute

        const char* Kc = Ks0 + cur * 8192;
        const char* Vc = Vs0 + cur * 8192;

        // ---- S^T = K Q^T over d-chunks of 16 ----
        f32x16 s0 = zero16(), s1 = zero16();
        __builtin_amdgcn_s_setprio(1);
        #pragma unroll
        for (int c4 = 0; c4 < 4; ++c4) {
            int col = c4 * 32 + hi * 16;
            short8 kf0 = *reinterpret_cast<const short8*>(Kc + ((lam * 128 + col) ^ swz));
            s0 = mfma32(kf0, qf[c4], s0);
            short8 kf1 = *reinterpret_cast<const short8*>(Kc + (((lam + 32) * 128 + col) ^ swz));
            s1 = mfma32(kf1, qf[c4], s1);
        }
        __builtin_amdgcn_s_setprio(0);

        // ---- online softmax (scale pre-folded into q); max3-fusable chain; defer THR=8 ----
        float tm = fmaxf(s0[0], s1[0]);
        #pragma unroll
        for (int r = 1; r < 16; ++r) tm = fmaxf(tm, fmaxf(s0[r], s1[r]));
        float tmax = red_max32(tm);
        if (__any(tmax - m_run > 8.0f)) {
            float mnew = fmaxf(m_run, tmax);
            float alpha = exp2f(m_run - mnew);
            m_run = mnew;
            #pragma unroll
            for (int r = 0; r < 16; ++r) {
                o0[r] *= alpha; o1[r] *= alpha; lacc[r] *= alpha;
            }
        }
        float p0[16], p1[16];
        #pragma unroll
        for (int r = 0; r < 16; ++r) p0[r] = exp2f(s0[r] - m_run);
        #pragma unroll
        for (int r = 0; r < 16; ++r) p1[r] = exp2f(s1[r] - m_run);

        // ---- P -> bf16 A-frags: cvt_pk + permlane32_swap cross-half exchange ----
        short8 pa[4];
        #pragma unroll
        for (int blk = 0; blk < 2; ++blk) {
            const float* p = blk ? p1 : p0;
            #pragma unroll
            for (int jt = 0; jt < 2; ++jt) {
                unsigned a0 = cvt_pk_bf16(p[jt * 8 + 0], p[jt * 8 + 1]);
                unsigned a1 = cvt_pk_bf16(p[jt * 8 + 2], p[jt * 8 + 3]);
                unsigned b0 = cvt_pk_bf16(p[jt * 8 + 4], p[jt * 8 + 5]);
                unsigned b1 = cvt_pk_bf16(p[jt * 8 + 6], p[jt * 8 + 7]);
                uint2 pr0 = permswap(a0, b0);
                uint2 pr1 = permswap(a1, b1);
                uint4 w;
                w.x = pr0.x;
                w.y = pr1.x;
                w.z = pr0.y;
                w.w = pr1.y;
                pa[blk * 2 + jt] = __builtin_bit_cast(short8, w);
            }
        }

        // ---- O^T += V^T P (+ l via ones-MFMA): d on reg-rows, q on lanes ----
        __builtin_amdgcn_s_setprio(1);
        #pragma unroll
        for (int jt = 0; jt < 4; ++jt) {
            int col = jt * 32 + hi * 16;
            short8 vf0 = *reinterpret_cast<const short8*>(Vc + ((lam * 128 + col) ^ swz));
            o0 = mfma32(vf0, pa[jt], o0);
            short8 vf1 = *reinterpret_cast<const short8*>(Vc + (((lam + 32) * 128 + col) ^ swz));
            o1 = mfma32(vf1, pa[jt], o1);
            lacc = mfma32(ones, pa[jt], lacc);
        }
        __builtin_amdgcn_s_setprio(0);
    }

    float l_run = lacc[0];

    // ---- split-KV merge: upper-half waves publish (o, m, l); lower-half merges ----
    __syncthreads();
    float* pb = (float*)(smem + pair * 8704);   // [64 lanes][34 f32]
    if (half) {
        #pragma unroll
        for (int r = 0; r < 16; ++r) {
            pb[lane * 34 + r] = o0[r];
            pb[lane * 34 + 16 + r] = o1[r];
        }
        pb[lane * 34 + 32] = m_run;
        pb[lane * 34 + 33] = l_run;
    }
    __syncthreads();
    if (half) return;

    float mb = pb[lane * 34 + 32], lb = pb[lane * 34 + 33];
    float m = fmaxf(m_run, mb);
    float wa = exp2f(m_run - m), wb = exp2f(mb - m);
    float l = l_run * wa + lb * wb;
    float rinv = 1.0f / l;
    #pragma unroll
    for (int r = 0; r < 16; ++r) {
        o0[r] = o0[r] * wa + pb[lane * 34 + r] * wb;
        o1[r] = o1[r] * wa + pb[lane * 34 + 16 + r] * wb;
    }

    // ---- epilogue: O[q][d] = o[d-reg][q] / l ; write [B][T][H*64] ----
    int b_ = bh >> 4, h_ = bh & 15;
    unsigned short* Orow = O + ((size_t)(b_ * 2048) + q) * 1024 + h_ * 64;
    #pragma unroll
    for (int rq = 0; rq < 4; ++rq) {
        ushort4 w0, w1;
        w0.x = f2bf(o0[rq * 4 + 0] * rinv);
        w0.y = f2bf(o0[rq * 4 + 1] * rinv);
        w0.z = f2bf(o0[rq * 4 + 2] * rinv);
        w0.w = f2bf(o0[rq * 4 + 3] * rinv);
        w1.x = f2bf(o1[rq * 4 + 0] * rinv);
        w1.y = f2bf(o1[rq * 4 + 1] * rinv);
        w1.z = f2bf(o1[rq * 4 + 2] * rinv);
        w1.w = f2bf(o1[rq * 4 + 3] * rinv);
        int d0 = rq * 8 + hi * 4;
        *reinterpret_cast<ushort4*>(Orow + d0) = w0;
        *reinterpret_cast<ushort4*>(Orow + 32 + d0) = w1;
    }
}

// ---------------- output GEMM + bias, fp32 out ----------------
__global__ __launch_bounds__(256) void out_gemm_kernel(
    const unsigned short* __restrict__ Aattn, const unsigned short* __restrict__ W,
    const float* __restrict__ bias, float* __restrict__ out) {
    __shared__ unsigned short As[2][128 * 64];
    __shared__ unsigned short Bs[2][128 * 64];
    const int K = 1024, N = 1024;
    int flat = blockIdx.x + 8 * blockIdx.y;
    int swzb = (flat & 7) * 32 + (flat >> 3);
    int m0 = (swzb >> 3) * 128, n0 = (swzb & 7) * 128;
    f32x4 acc[4][4];
    #pragma unroll
    for (int i = 0; i < 4; ++i)
        #pragma unroll
        for (int j = 0; j < 4; ++j) acc[i][j] = zero4();

    gemm_mainloop_128x128(Aattn, W, K, m0, n0, &As[0][0], &Bs[0][0], acc);

    int tid = threadIdx.x;
    int wave = tid >> 6, lane = tid & 63;
    int wm = wave >> 1, wn = wave & 1;
    int g = lane >> 4, c = lane & 15;
    int mbase = m0 + wm * 64, nbase = n0 + wn * 64;
    #pragma unroll
    for (int mt = 0; mt < 4; ++mt)
        #pragma unroll
        for (int nt = 0; nt < 4; ++nt) {
            int n = nbase + nt * 16 + c;
            float bn = bias[n];
            #pragma unroll
            for (int r = 0; r < 4; ++r) {
                int m = mbase + mt * 16 + g * 4 + r;
                out[(size_t)m * N + n] = acc[mt][nt][r] + bn;
            }
        }
}

extern "C" void kernel_launch(void* const* d_in, const int* in_sizes, int n_in,
                              void* d_out, int out_size, void* d_ws, size_t ws_size,
                              hipStream_t stream) {
    (void)in_sizes; (void)n_in; (void)out_size; (void)ws_size;
    const float* x     = (const float*)d_in[0];
    const float* w_qkv = (const float*)d_in[1];
    const float* b_qkv = (const float*)d_in[2];
    const float* w_out = (const float*)d_in[3];
    const float* b_out = (const float*)d_in[4];
    float* out = (float*)d_out;

    const int B = 2, T = 2048, D = 1024;
    const int M = B * T;                 // 4096
    const size_t MB = 1024 * 1024;

    char* ws = (char*)d_ws;
    unsigned short* xb    = (unsigned short*)(ws);            // 8 MB  x bf16 [4096][1024]
    unsigned short* wqkvb = (unsigned short*)(ws + 8 * MB);   // 6 MB  w_qkv bf16
    unsigned short* woutb = (unsigned short*)(ws + 14 * MB);  // 2 MB  w_out bf16
    unsigned short* qb    = (unsigned short*)(ws + 16 * MB);  // 8 MB  q (pre-scaled) [32][2048][64]
    unsigned short* kb    = (unsigned short*)(ws + 24 * MB);  // 8 MB  k
    unsigned short* vtb   = (unsigned short*)(ws + 32 * MB);  // 8 MB  v^T [32][64][2048]
    unsigned short* attnb = (unsigned short*)(ws + 40 * MB);  // 8 MB  attn out [4096][1024]
    float2* tab           = (float2*)(ws + 48 * MB);          // 512 KB rope table

    prep_kernel<<<dim3((2097152 + 65536) / 256), dim3(256), 0, stream>>>(
        x, w_qkv, w_out, xb, wqkvb, woutb, tab);
    qkv_gemm_kernel<<<dim3(3 * D / 128, M / 128), dim3(256), 0, stream>>>(xb, wqkvb, b_qkv, tab, qb, kb, vtb);
    attn_kernel<<<dim3(T / 128, B * 16), dim3(512), 0, stream>>>(qb, kb, vtb, attnb);
    out_gemm_kernel<<<dim3(D / 128, M / 128), dim3(256), 0, stream>>>(attnb, woutb, b_out, out);
}

// Round 11
// 153.209 us; speedup vs baseline: 1.1330x; 1.0859x over previous
//
#include <hip/hip_runtime.h>
#include <cstdint>
#include <cstddef>

typedef __attribute__((ext_vector_type(8))) short short8;
typedef __attribute__((ext_vector_type(8))) __bf16 bf16x8;
typedef __attribute__((ext_vector_type(4))) float f32x4;
typedef __attribute__((ext_vector_type(16))) float f32x16;
typedef __attribute__((ext_vector_type(4))) unsigned int uint32x4;

#define LOG2E 1.44269504088896340736f

__device__ __forceinline__ unsigned short f2bf(float f) {
    unsigned int u = __builtin_bit_cast(unsigned int, f);
    u += 0x7fffu + ((u >> 16) & 1u);
    return (unsigned short)(u >> 16);
}

__device__ __forceinline__ f32x4 zero4() {
    f32x4 z; z.x = 0.f; z.y = 0.f; z.z = 0.f; z.w = 0.f; return z;
}
__device__ __forceinline__ f32x16 zero16() {
    f32x16 z;
    #pragma unroll
    for (int i = 0; i < 16; ++i) z[i] = 0.f;
    return z;
}

__device__ __forceinline__ f32x4 mfma16(short8 a, short8 b, f32x4 c) {
    return __builtin_amdgcn_mfma_f32_16x16x32_bf16(
        __builtin_bit_cast(bf16x8, a), __builtin_bit_cast(bf16x8, b), c, 0, 0, 0);
}
__device__ __forceinline__ f32x16 mfma32(short8 a, short8 b, f32x16 c) {
    return __builtin_amdgcn_mfma_f32_32x32x16_bf16(
        __builtin_bit_cast(bf16x8, a), __builtin_bit_cast(bf16x8, b), c, 0, 0, 0);
}

__device__ __forceinline__ unsigned int cvt_pk_bf16(float lo, float hi) {
    unsigned int r;
    asm("v_cvt_pk_bf16_f32 %0, %1, %2" : "=v"(r) : "v"(lo), "v"(hi));
    return r;
}

// v_permlane32_swap_b32 (CDNA4 ISA): for l in 0..31: vdst[l+32] <-> vsrc[l].
// ret.x (new vdst): lanes<32 = x[l],    lanes>=32 = y[l-32]
// ret.y (new vsrc): lanes<32 = x[l+32], lanes>=32 = y[l]
__device__ __forceinline__ uint2 permswap(unsigned x, unsigned y) {
#if __has_builtin(__builtin_amdgcn_permlane32_swap)
    auto r = __builtin_amdgcn_permlane32_swap(x, y, false, false);
    return make_uint2(r[0], r[1]);
#else
    int lane = threadIdx.x & 63;
    unsigned sy = __shfl_xor(y, 32), sx = __shfl_xor(x, 32);
    return make_uint2((lane < 32) ? x : sy, (lane < 32) ? sx : y);
#endif
}
__device__ __forceinline__ float red_max32(float v) {
    unsigned u = __builtin_bit_cast(unsigned, v);
    uint2 p = permswap(u, u);
    return fmaxf(__builtin_bit_cast(float, p.x), __builtin_bit_cast(float, p.y));
}

// async 16B global->LDS: per-lane g, wave-uniform lds base l; HW writes l + lane*16
__device__ __forceinline__ void gload_lds16(const void* g, void* l, int lane) {
#if __has_builtin(__builtin_amdgcn_global_load_lds)
    __builtin_amdgcn_global_load_lds(
        (const __attribute__((address_space(1))) void*)g,
        (__attribute__((address_space(3))) void*)l, 16, 0, 0);
    (void)lane;
#else
    reinterpret_cast<int4*>(l)[lane] = *reinterpret_cast<const int4*>(g);
#endif
}

// ---------------- fused prep: 3x fp32->bf16 cast + RoPE table ----------------
__global__ __launch_bounds__(256) void prep_kernel(
    const float* __restrict__ x, const float* __restrict__ wq,
    const float* __restrict__ wo,
    unsigned short* __restrict__ xb, unsigned short* __restrict__ wqb,
    unsigned short* __restrict__ wob, float2* __restrict__ tab) {
    const int S0 = 1048576, S1 = 786432, S2 = 262144;   // float4 counts
    int i = blockIdx.x * 256 + threadIdx.x;
    const float* src; unsigned short* dst; int j;
    if (i < S0) { src = x; dst = xb; j = i; }
    else if (i < S0 + S1) { src = wq; dst = wqb; j = i - S0; }
    else if (i < S0 + S1 + S2) { src = wo; dst = wob; j = i - S0 - S1; }
    else {
        int idx = i - (S0 + S1 + S2);
        if (idx < 2048 * 32) {
            int t = idx >> 5, ii = idx & 31;
            float inv_freq = powf(10000.0f, -(float)ii / 32.0f);
            float ang = (float)t * inv_freq;
            tab[idx] = make_float2(cosf(ang), sinf(ang));
        }
        return;
    }
    float4 v = reinterpret_cast<const float4*>(src)[j];
    ushort4 o;
    o.x = f2bf(v.x); o.y = f2bf(v.y); o.z = f2bf(v.z); o.w = f2bf(v.w);
    reinterpret_cast<ushort4*>(dst)[j] = o;
}

// ---------------- shared 128x128 NT bf16 GEMM mainloop (BK=64), double-buffered ----------------
// 8 waves (512 thr): wave grid 4x2, each wave owns a 32x64 sub-tile (acc[2][4]).
// 2 blocks/CU (LDS 64KB) x 8 waves = 16 waves/CU = 4/SIMD — TLP hides the
// per-iteration vmcnt drain that 4-wave blocks (1.3/SIMD) could not.
__device__ __forceinline__ void gemm_mainloop_128x128(
    const unsigned short* __restrict__ A, const unsigned short* __restrict__ B,
    int K, int m0, int n0, unsigned short* As, unsigned short* Bs, f32x4 acc[2][4]) {
    int tid = threadIdx.x;
    int wave = tid >> 6, lane = tid & 63;
    int wm = wave >> 1, wn = wave & 1;
    int g = lane >> 4, c = lane & 15;
    const int NS = K >> 6;

    auto stage = [&](int buf, int k0) {
        #pragma unroll
        for (int i = 0; i < 2; ++i) {
            int call = wave * 2 + i;          // 0..15
            int s = call * 64 + lane;         // 0..1023
            int row = s >> 3, c8 = s & 7;
            int csw = (c8 ^ (row & 7)) << 3;
            gload_lds16(A + (size_t)(m0 + row) * K + k0 + csw,
                        (char*)As + buf * 16384 + call * 1024, lane);
            gload_lds16(B + (size_t)(n0 + row) * K + k0 + csw,
                        (char*)Bs + buf * 16384 + call * 1024, lane);
        }
    };

    stage(0, 0);   // tile 0 in flight

    #pragma unroll 1
    for (int t = 0; t < NS; ++t) {
        int cur = t & 1;
        asm volatile("s_waitcnt vmcnt(0) lgkmcnt(0)" ::: "memory");
        __builtin_amdgcn_s_barrier();    // all waves' tile-t resident; buf[cur^1] free
        __builtin_amdgcn_sched_barrier(0);
        if (t + 1 < NS) stage(cur ^ 1, (t + 1) * 64);   // in flight across compute

        const char* Ac = (const char*)As + cur * 16384;
        const char* Bc = (const char*)Bs + cur * 16384;
        #pragma unroll
        for (int kg = 0; kg < 2; ++kg) {
            short8 af[2], bfr[4];
            #pragma unroll
            for (int mt = 0; mt < 2; ++mt) {
                int row = wm * 32 + mt * 16 + c;
                af[mt] = *reinterpret_cast<const short8*>(Ac +
                    ((row * 128 + kg * 64 + g * 16) ^ ((row & 7) << 4)));
            }
            #pragma unroll
            for (int nt = 0; nt < 4; ++nt) {
                int row = wn * 64 + nt * 16 + c;
                bfr[nt] = *reinterpret_cast<const short8*>(Bc +
                    ((row * 128 + kg * 64 + g * 16) ^ ((row & 7) << 4)));
            }
            __builtin_amdgcn_s_setprio(1);
            #pragma unroll
            for (int mt = 0; mt < 2; ++mt)
                #pragma unroll
                for (int nt = 0; nt < 4; ++nt)
                    acc[mt][nt] = mfma16(af[mt], bfr[nt], acc[mt][nt]);
            __builtin_amdgcn_s_setprio(0);
        }
    }
}

// ---------------- QKV GEMM + bias + RoPE; q (pre-scaled by 0.125*log2e), k -> [B*H][T][64], v -> [B*H][64][T] ----------------
__global__ __launch_bounds__(512, 2) void qkv_gemm_kernel(
    const unsigned short* __restrict__ X, const unsigned short* __restrict__ W,
    const float* __restrict__ bias, const float2* __restrict__ tab,
    unsigned short* __restrict__ q, unsigned short* __restrict__ k,
    unsigned short* __restrict__ vt) {
    __shared__ unsigned short As[2][128 * 64];
    __shared__ unsigned short Bs[2][128 * 64];
    const int K = 1024;
    const float SCL = 0.125f * LOG2E;   // folded into q
    int flat = blockIdx.x + 24 * blockIdx.y;
    int swzb = (flat & 7) * 96 + (flat >> 3);
    int m0 = (swzb / 24) * 128, n0 = (swzb % 24) * 128;
    f32x4 acc[2][4];
    #pragma unroll
    for (int i = 0; i < 2; ++i)
        #pragma unroll
        for (int j = 0; j < 4; ++j) acc[i][j] = zero4();

    gemm_mainloop_128x128(X, W, K, m0, n0, &As[0][0], &Bs[0][0], acc);

    int tid = threadIdx.x;
    int wave = tid >> 6, lane = tid & 63;
    int wm = wave >> 1, wn = wave & 1;
    int g = lane >> 4, c = lane & 15;
    int mbase = m0 + wm * 32, nbase = n0 + wn * 64;
    #pragma unroll
    for (int mt = 0; mt < 2; ++mt) {
        #pragma unroll
        for (int nt = 0; nt < 4; ++nt) {
            f32x4 a = acc[mt][nt];
            int n = nbase + nt * 16 + c;
            int s = n >> 10;            // 0=q 1=k 2=v
            int h = (n >> 6) & 15;
            int d = n & 63;
            float bn = bias[n];
            #pragma unroll
            for (int r = 0; r < 4; ++r) {
                int m = mbase + mt * 16 + g * 4 + r;
                int bb = m >> 11, t = m & 2047;
                float val = a[r] + bn;
                float partner = __shfl_xor(val, 1);
                int bh = bb * 16 + h;
                if (s == 2) {
                    vt[((size_t)bh * 64 + d) * 2048 + t] = f2bf(val);
                } else {
                    int i2 = d >> 1;
                    float2 cs = tab[t * 32 + i2];
                    float outv; int dout;
                    if ((d & 1) == 0) { outv = val * cs.x - partner * cs.y; dout = i2; }
                    else              { outv = partner * cs.y + val * cs.x; dout = 32 + i2; }
                    if (s == 0) outv *= SCL;
                    (s == 0 ? q : k)[((size_t)bh * 2048 + t) * 64 + dout] = f2bf(outv);
                }
            }
        }
    }
}

// ---------------- flash attention: swapped-operand 32x32, SPLIT-KV 8-wave blocks ----------------
// Waves 0-3: j in [0,1024); waves 4-7: j in [1024,2048) for the SAME 128 q-rows.
// __launch_bounds__(512, 2): 256-VGPR budget (512,4 forced a 128-reg cap -> spill).
__global__ __launch_bounds__(512, 2) void attn_kernel(
    const unsigned short* __restrict__ Q, const unsigned short* __restrict__ Kin,
    const unsigned short* __restrict__ VT, unsigned short* __restrict__ O) {
    __shared__ int4 smem4[65536 / 16];     // 64 KB
    char* smem = (char*)smem4;
    const int T = 2048, NT = 16;           // 16 tiles of 64 j per half
    int flat = blockIdx.x + 16 * blockIdx.y;
    int swzb = (flat & 7) * 64 + (flat >> 3);
    int bh = swzb >> 4;
    int qt = swzb & 15;
    int tid = threadIdx.x, wave = tid >> 6, lane = tid & 63;
    int lam = lane & 31, hi = lane >> 5;
    int pair = wave & 3, half = wave >> 2;
    int q = qt * 128 + pair * 32 + lam;

    const unsigned short* Qb = Q + ((size_t)bh * T + q) * 64;
    const unsigned short* Kb = Kin + (size_t)bh * T * 64;
    const unsigned short* VTb = VT + (size_t)bh * 64 * T;

    // Q fragments: load + pin in prologue (keeps the loads out of the loop).
    uint32x4 qtmp[4];
    #pragma unroll
    for (int c4 = 0; c4 < 4; ++c4)
        qtmp[c4] = *reinterpret_cast<const uint32x4*>(Qb + c4 * 16 + hi * 8);
    #pragma unroll
    for (int c4 = 0; c4 < 4; ++c4)
        asm volatile("" : "+v"(qtmp[c4]));
    short8 qf[4];
    #pragma unroll
    for (int c4 = 0; c4 < 4; ++c4) qf[c4] = __builtin_bit_cast(short8, qtmp[c4]);

    short8 ones;
    #pragma unroll
    for (int i = 0; i < 8; ++i) ones[i] = (short)0x3F80;   // bf16 1.0

    f32x16 o0 = zero16(), o1 = zero16(), lacc = zero16();
    float m_run = -1e30f;
    int swz = (lam & 7) << 4;

    // this half's LDS: [buf0|buf1] 8KB each
    char* Ks0 = smem + half * 16384;
    char* Vs0 = smem + 32768 + half * 16384;

    // staging: 4 waves of a half fill its 8KB K-tile + 8KB V-tile (4 loads/wave)
    auto stage = [&](int buf, int t) {
        int j0 = half * 1024 + t * 64;
        #pragma unroll
        for (int i = 0; i < 2; ++i) {
            int call = pair * 2 + i;           // 0..7
            int s = call * 64 + lane;
            int row = s >> 3, c8 = s & 7;
            int csw = (c8 ^ (row & 7)) << 3;
            gload_lds16(Kb + (size_t)(j0 + row) * 64 + csw,
                        Ks0 + buf * 8192 + call * 1024, lane);
            gload_lds16(VTb + (size_t)row * T + j0 + csw,
                        Vs0 + buf * 8192 + call * 1024, lane);
        }
    };

    stage(0, 0);     // prologue: tile 0 in flight

    #pragma unroll 1
    for (int t = 0; t < NT; ++t) {
        int cur = t & 1;
        // my tile-t loads done (one full compute phase in flight); my ds_reads drained
        asm volatile("s_waitcnt vmcnt(0) lgkmcnt(0)" ::: "memory");
        __builtin_amdgcn_s_barrier();
        __builtin_amdgcn_sched_barrier(0);
        if (t + 1 < NT) stage(cur ^ 1, t + 1);   // in flight across compute

        const char* Kc = Ks0 + cur * 8192;
        const char* Vc = Vs0 + cur * 8192;

        // ---- S^T = K Q^T over d-chunks of 16 ----
        f32x16 s0 = zero16(), s1 = zero16();
        __builtin_amdgcn_s_setprio(1);
        #pragma unroll
        for (int c4 = 0; c4 < 4; ++c4) {
            int col = c4 * 32 + hi * 16;
            short8 kf0 = *reinterpret_cast<const short8*>(Kc + ((lam * 128 + col) ^ swz));
            s0 = mfma32(kf0, qf[c4], s0);
            short8 kf1 = *reinterpret_cast<const short8*>(Kc + (((lam + 32) * 128 + col) ^ swz));
            s1 = mfma32(kf1, qf[c4], s1);
        }
        __builtin_amdgcn_s_setprio(0);

        // ---- online softmax (scale pre-folded into q); max3-fusable chain; defer THR=8 ----
        float tm = fmaxf(s0[0], s1[0]);
        #pragma unroll
        for (int r = 1; r < 16; ++r) tm = fmaxf(tm, fmaxf(s0[r], s1[r]));
        float tmax = red_max32(tm);
        if (__any(tmax - m_run > 8.0f)) {
            float mnew = fmaxf(m_run, tmax);
            float alpha = exp2f(m_run - mnew);
            m_run = mnew;
            #pragma unroll
            for (int r = 0; r < 16; ++r) {
                o0[r] *= alpha; o1[r] *= alpha; lacc[r] *= alpha;
            }
        }
        float p0[16], p1[16];
        #pragma unroll
        for (int r = 0; r < 16; ++r) p0[r] = exp2f(s0[r] - m_run);
        #pragma unroll
        for (int r = 0; r < 16; ++r) p1[r] = exp2f(s1[r] - m_run);

        // ---- P -> bf16 A-frags: cvt_pk + permlane32_swap cross-half exchange ----
        short8 pa[4];
        #pragma unroll
        for (int blk = 0; blk < 2; ++blk) {
            const float* p = blk ? p1 : p0;
            #pragma unroll
            for (int jt = 0; jt < 2; ++jt) {
                unsigned a0 = cvt_pk_bf16(p[jt * 8 + 0], p[jt * 8 + 1]);
                unsigned a1 = cvt_pk_bf16(p[jt * 8 + 2], p[jt * 8 + 3]);
                unsigned b0 = cvt_pk_bf16(p[jt * 8 + 4], p[jt * 8 + 5]);
                unsigned b1 = cvt_pk_bf16(p[jt * 8 + 6], p[jt * 8 + 7]);
                uint2 pr0 = permswap(a0, b0);
                uint2 pr1 = permswap(a1, b1);
                uint4 w;
                w.x = pr0.x;
                w.y = pr1.x;
                w.z = pr0.y;
                w.w = pr1.y;
                pa[blk * 2 + jt] = __builtin_bit_cast(short8, w);
            }
        }

        // ---- O^T += V^T P (+ l via ones-MFMA): d on reg-rows, q on lanes ----
        __builtin_amdgcn_s_setprio(1);
        #pragma unroll
        for (int jt = 0; jt < 4; ++jt) {
            int col = jt * 32 + hi * 16;
            short8 vf0 = *reinterpret_cast<const short8*>(Vc + ((lam * 128 + col) ^ swz));
            o0 = mfma32(vf0, pa[jt], o0);
            short8 vf1 = *reinterpret_cast<const short8*>(Vc + (((lam + 32) * 128 + col) ^ swz));
            o1 = mfma32(vf1, pa[jt], o1);
            lacc = mfma32(ones, pa[jt], lacc);
        }
        __builtin_amdgcn_s_setprio(0);
    }

    float l_run = lacc[0];

    // ---- split-KV merge: upper-half waves publish (o, m, l); lower-half merges ----
    __syncthreads();
    float* pb = (float*)(smem + pair * 8704);   // [64 lanes][34 f32]
    if (half) {
        #pragma unroll
        for (int r = 0; r < 16; ++r) {
            pb[lane * 34 + r] = o0[r];
            pb[lane * 34 + 16 + r] = o1[r];
        }
        pb[lane * 34 + 32] = m_run;
        pb[lane * 34 + 33] = l_run;
    }
    __syncthreads();
    if (half) return;

    float mb = pb[lane * 34 + 32], lb = pb[lane * 34 + 33];
    float m = fmaxf(m_run, mb);
    float wa = exp2f(m_run - m), wb = exp2f(mb - m);
    float l = l_run * wa + lb * wb;
    float rinv = 1.0f / l;
    #pragma unroll
    for (int r = 0; r < 16; ++r) {
        o0[r] = o0[r] * wa + pb[lane * 34 + r] * wb;
        o1[r] = o1[r] * wa + pb[lane * 34 + 16 + r] * wb;
    }

    // ---- epilogue: O[q][d] = o[d-reg][q] / l ; write [B][T][H*64] ----
    int b_ = bh >> 4, h_ = bh & 15;
    unsigned short* Orow = O + ((size_t)(b_ * 2048) + q) * 1024 + h_ * 64;
    #pragma unroll
    for (int rq = 0; rq < 4; ++rq) {
        ushort4 w0, w1;
        w0.x = f2bf(o0[rq * 4 + 0] * rinv);
        w0.y = f2bf(o0[rq * 4 + 1] * rinv);
        w0.z = f2bf(o0[rq * 4 + 2] * rinv);
        w0.w = f2bf(o0[rq * 4 + 3] * rinv);
        w1.x = f2bf(o1[rq * 4 + 0] * rinv);
        w1.y = f2bf(o1[rq * 4 + 1] * rinv);
        w1.z = f2bf(o1[rq * 4 + 2] * rinv);
        w1.w = f2bf(o1[rq * 4 + 3] * rinv);
        int d0 = rq * 8 + hi * 4;
        *reinterpret_cast<ushort4*>(Orow + d0) = w0;
        *reinterpret_cast<ushort4*>(Orow + 32 + d0) = w1;
    }
}

// ---------------- output GEMM + bias, fp32 out ----------------
__global__ __launch_bounds__(512, 2) void out_gemm_kernel(
    const unsigned short* __restrict__ Aattn, const unsigned short* __restrict__ W,
    const float* __restrict__ bias, float* __restrict__ out) {
    __shared__ unsigned short As[2][128 * 64];
    __shared__ unsigned short Bs[2][128 * 64];
    const int K = 1024, N = 1024;
    int flat = blockIdx.x + 8 * blockIdx.y;
    int swzb = (flat & 7) * 32 + (flat >> 3);
    int m0 = (swzb >> 3) * 128, n0 = (swzb & 7) * 128;
    f32x4 acc[2][4];
    #pragma unroll
    for (int i = 0; i < 2; ++i)
        #pragma unroll
        for (int j = 0; j < 4; ++j) acc[i][j] = zero4();

    gemm_mainloop_128x128(Aattn, W, K, m0, n0, &As[0][0], &Bs[0][0], acc);

    int tid = threadIdx.x;
    int wave = tid >> 6, lane = tid & 63;
    int wm = wave >> 1, wn = wave & 1;
    int g = lane >> 4, c = lane & 15;
    int mbase = m0 + wm * 32, nbase = n0 + wn * 64;
    #pragma unroll
    for (int mt = 0; mt < 2; ++mt)
        #pragma unroll
        for (int nt = 0; nt < 4; ++nt) {
            int n = nbase + nt * 16 + c;
            float bn = bias[n];
            #pragma unroll
            for (int r = 0; r < 4; ++r) {
                int m = mbase + mt * 16 + g * 4 + r;
                out[(size_t)m * N + n] = acc[mt][nt][r] + bn;
            }
        }
}

extern "C" void kernel_launch(void* const* d_in, const int* in_sizes, int n_in,
                              void* d_out, int out_size, void* d_ws, size_t ws_size,
                              hipStream_t stream) {
    (void)in_sizes; (void)n_in; (void)out_size; (void)ws_size;
    const float* x     = (const float*)d_in[0];
    const float* w_qkv = (const float*)d_in[1];
    const float* b_qkv = (const float*)d_in[2];
    const float* w_out = (const float*)d_in[3];
    const float* b_out = (const float*)d_in[4];
    float* out = (float*)d_out;

    const int B = 2, T = 2048, D = 1024;
    const int M = B * T;                 // 4096
    const size_t MB = 1024 * 1024;

    char* ws = (char*)d_ws;
    unsigned short* xb    = (unsigned short*)(ws);            // 8 MB  x bf16 [4096][1024]
    unsigned short* wqkvb = (unsigned short*)(ws + 8 * MB);   // 6 MB  w_qkv bf16
    unsigned short* woutb = (unsigned short*)(ws + 14 * MB);  // 2 MB  w_out bf16
    unsigned short* qb    = (unsigned short*)(ws + 16 * MB);  // 8 MB  q (pre-scaled) [32][2048][64]
    unsigned short* kb    = (unsigned short*)(ws + 24 * MB);  // 8 MB  k
    unsigned short* vtb   = (unsigned short*)(ws + 32 * MB);  // 8 MB  v^T [32][64][2048]
    unsigned short* attnb = (unsigned short*)(ws + 40 * MB);  // 8 MB  attn out [4096][1024]
    float2* tab           = (float2*)(ws + 48 * MB);          // 512 KB rope table

    prep_kernel<<<dim3((2097152 + 65536) / 256), dim3(256), 0, stream>>>(
        x, w_qkv, w_out, xb, wqkvb, woutb, tab);
    qkv_gemm_kernel<<<dim3(3 * D / 128, M / 128), dim3(512), 0, stream>>>(xb, wqkvb, b_qkv, tab, qb, kb, vtb);
    attn_kernel<<<dim3(T / 128, B * 16), dim3(512), 0, stream>>>(qb, kb, vtb, attnb);
    out_gemm_kernel<<<dim3(D / 128, M / 128), dim3(512), 0, stream>>>(attnb, woutb, b_out, out);
}

// Round 12
// 143.928 us; speedup vs baseline: 1.2060x; 1.0645x over previous
//
#include <hip/hip_runtime.h>
#include <cstdint>
#include <cstddef>

typedef __attribute__((ext_vector_type(8))) short short8;
typedef __attribute__((ext_vector_type(8))) __bf16 bf16x8;
typedef __attribute__((ext_vector_type(4))) float f32x4;
typedef __attribute__((ext_vector_type(16))) float f32x16;
typedef __attribute__((ext_vector_type(4))) unsigned int uint32x4;

#define LOG2E 1.44269504088896340736f

__device__ __forceinline__ unsigned short f2bf(float f) {
    unsigned int u = __builtin_bit_cast(unsigned int, f);
    u += 0x7fffu + ((u >> 16) & 1u);
    return (unsigned short)(u >> 16);
}

__device__ __forceinline__ f32x4 zero4() {
    f32x4 z; z.x = 0.f; z.y = 0.f; z.z = 0.f; z.w = 0.f; return z;
}
__device__ __forceinline__ f32x16 zero16() {
    f32x16 z;
    #pragma unroll
    for (int i = 0; i < 16; ++i) z[i] = 0.f;
    return z;
}

__device__ __forceinline__ f32x4 mfma16(short8 a, short8 b, f32x4 c) {
    return __builtin_amdgcn_mfma_f32_16x16x32_bf16(
        __builtin_bit_cast(bf16x8, a), __builtin_bit_cast(bf16x8, b), c, 0, 0, 0);
}
__device__ __forceinline__ f32x16 mfma32(short8 a, short8 b, f32x16 c) {
    return __builtin_amdgcn_mfma_f32_32x32x16_bf16(
        __builtin_bit_cast(bf16x8, a), __builtin_bit_cast(bf16x8, b), c, 0, 0, 0);
}

__device__ __forceinline__ unsigned int cvt_pk_bf16(float lo, float hi) {
    unsigned int r;
    asm("v_cvt_pk_bf16_f32 %0, %1, %2" : "=v"(r) : "v"(lo), "v"(hi));
    return r;
}

// v_permlane32_swap_b32 (CDNA4 ISA): for l in 0..31: vdst[l+32] <-> vsrc[l].
// ret.x (new vdst): lanes<32 = x[l],    lanes>=32 = y[l-32]
// ret.y (new vsrc): lanes<32 = x[l+32], lanes>=32 = y[l]
__device__ __forceinline__ uint2 permswap(unsigned x, unsigned y) {
#if __has_builtin(__builtin_amdgcn_permlane32_swap)
    auto r = __builtin_amdgcn_permlane32_swap(x, y, false, false);
    return make_uint2(r[0], r[1]);
#else
    int lane = threadIdx.x & 63;
    unsigned sy = __shfl_xor(y, 32), sx = __shfl_xor(x, 32);
    return make_uint2((lane < 32) ? x : sy, (lane < 32) ? sx : y);
#endif
}
__device__ __forceinline__ float red_max32(float v) {
    unsigned u = __builtin_bit_cast(unsigned, v);
    uint2 p = permswap(u, u);
    return fmaxf(__builtin_bit_cast(float, p.x), __builtin_bit_cast(float, p.y));
}

// async 16B global->LDS: per-lane g, wave-uniform lds base l; HW writes l + lane*16
__device__ __forceinline__ void gload_lds16(const void* g, void* l, int lane) {
#if __has_builtin(__builtin_amdgcn_global_load_lds)
    __builtin_amdgcn_global_load_lds(
        (const __attribute__((address_space(1))) void*)g,
        (__attribute__((address_space(3))) void*)l, 16, 0, 0);
    (void)lane;
#else
    reinterpret_cast<int4*>(l)[lane] = *reinterpret_cast<const int4*>(g);
#endif
}

// ---------------- fused prep: 3x fp32->bf16 cast + RoPE table ----------------
__global__ __launch_bounds__(256) void prep_kernel(
    const float* __restrict__ x, const float* __restrict__ wq,
    const float* __restrict__ wo,
    unsigned short* __restrict__ xb, unsigned short* __restrict__ wqb,
    unsigned short* __restrict__ wob, float2* __restrict__ tab) {
    const int S0 = 1048576, S1 = 786432, S2 = 262144;   // float4 counts
    int i = blockIdx.x * 256 + threadIdx.x;
    const float* src; unsigned short* dst; int j;
    if (i < S0) { src = x; dst = xb; j = i; }
    else if (i < S0 + S1) { src = wq; dst = wqb; j = i - S0; }
    else if (i < S0 + S1 + S2) { src = wo; dst = wob; j = i - S0 - S1; }
    else {
        int idx = i - (S0 + S1 + S2);
        if (idx < 2048 * 32) {
            int t = idx >> 5, ii = idx & 31;
            float inv_freq = powf(10000.0f, -(float)ii / 32.0f);
            float ang = (float)t * inv_freq;
            tab[idx] = make_float2(cosf(ang), sinf(ang));
        }
        return;
    }
    float4 v = reinterpret_cast<const float4*>(src)[j];
    ushort4 o;
    o.x = f2bf(v.x); o.y = f2bf(v.y); o.z = f2bf(v.z); o.w = f2bf(v.w);
    reinterpret_cast<ushort4*>(dst)[j] = o;
}

// ---------------- templated NT bf16 GEMM mainloop (BK=64), double-buffered ----------------
// 8 waves (512 thr) as WMG x WNG wave grid; per-wave sub-tile (BM/WMG) x (BN/WNG).
// 2 blocks/CU = 16 waves/CU = 4/SIMD.
template<int BM, int BN, int WMG, int WNG>
__device__ __forceinline__ void gemm_mainloop(
    const unsigned short* __restrict__ A, const unsigned short* __restrict__ B,
    int K, int m0, int n0, char* As, char* Bs,
    f32x4 (&acc)[BM / (WMG * 16)][BN / (WNG * 16)]) {
    constexpr int MT = BM / (WMG * 16), NTT = BN / (WNG * 16);
    constexpr int CA = BM / 64, CB = BN / 64;        // 16B chunks per thread
    constexpr int ABUF = BM * 128, BBUF = BN * 128;  // bytes per buffer
    int tid = threadIdx.x;
    int wave = tid >> 6, lane = tid & 63;
    int wm = wave / WNG, wn = wave % WNG;
    int g = lane >> 4, c = lane & 15;
    const int NS = K >> 6;

    auto stage = [&](int buf, int k0) {
        #pragma unroll
        for (int i = 0; i < CA; ++i) {
            int call = wave * CA + i;
            int s = call * 64 + lane;
            int row = s >> 3, c8 = s & 7;
            int csw = (c8 ^ (row & 7)) << 3;
            gload_lds16(A + (size_t)(m0 + row) * K + k0 + csw,
                        As + buf * ABUF + call * 1024, lane);
        }
        #pragma unroll
        for (int i = 0; i < CB; ++i) {
            int call = wave * CB + i;
            int s = call * 64 + lane;
            int row = s >> 3, c8 = s & 7;
            int csw = (c8 ^ (row & 7)) << 3;
            gload_lds16(B + (size_t)(n0 + row) * K + k0 + csw,
                        Bs + buf * BBUF + call * 1024, lane);
        }
    };

    stage(0, 0);   // tile 0 in flight

    #pragma unroll 1
    for (int t = 0; t < NS; ++t) {
        int cur = t & 1;
        asm volatile("s_waitcnt vmcnt(0)" ::: "memory");
        __builtin_amdgcn_s_barrier();    // all waves' tile-t resident; buf[cur^1] free
        __builtin_amdgcn_sched_barrier(0);
        if (t + 1 < NS) stage(cur ^ 1, (t + 1) * 64);   // in flight across compute

        const char* Ac = As + cur * ABUF;
        const char* Bc = Bs + cur * BBUF;
        #pragma unroll
        for (int kg = 0; kg < 2; ++kg) {
            short8 af[MT], bfr[NTT];
            #pragma unroll
            for (int mt = 0; mt < MT; ++mt) {
                int row = wm * (BM / WMG) + mt * 16 + c;
                af[mt] = *reinterpret_cast<const short8*>(Ac +
                    ((row * 128 + kg * 64 + g * 16) ^ ((row & 7) << 4)));
            }
            #pragma unroll
            for (int nt = 0; nt < NTT; ++nt) {
                int row = wn * (BN / WNG) + nt * 16 + c;
                bfr[nt] = *reinterpret_cast<const short8*>(Bc +
                    ((row * 128 + kg * 64 + g * 16) ^ ((row & 7) << 4)));
            }
            __builtin_amdgcn_s_setprio(1);
            #pragma unroll
            for (int mt = 0; mt < MT; ++mt)
                #pragma unroll
                for (int nt = 0; nt < NTT; ++nt)
                    acc[mt][nt] = mfma16(af[mt], bfr[nt], acc[mt][nt]);
            __builtin_amdgcn_s_setprio(0);
        }
    }
}

// ---------------- QKV GEMM (128x192 tile, grid 512 = one full generation) ----------------
// + bias + RoPE; q (pre-scaled by 0.125*log2e), k -> [B*H][T][64], v -> [B*H][64][T]
__global__ __launch_bounds__(512, 2) void qkv_gemm_kernel(
    const unsigned short* __restrict__ X, const unsigned short* __restrict__ W,
    const float* __restrict__ bias, const float2* __restrict__ tab,
    unsigned short* __restrict__ q, unsigned short* __restrict__ k,
    unsigned short* __restrict__ vt) {
    __shared__ char smem[80 * 1024];     // A dbuf 32K + B dbuf 48K
    const int K = 1024;
    const float SCL = 0.125f * LOG2E;    // folded into q
    // XCD swizzle, nwg=512: consecutive swzb within an XCD share the A m-panel
    int flat = blockIdx.x;
    int swzb = (flat & 7) * 64 + (flat >> 3);
    int m0 = (swzb >> 4) * 128, n0 = (swzb & 15) * 192;
    f32x4 acc[2][6];
    #pragma unroll
    for (int i = 0; i < 2; ++i)
        #pragma unroll
        for (int j = 0; j < 6; ++j) acc[i][j] = zero4();

    gemm_mainloop<128, 192, 4, 2>(X, W, K, m0, n0, smem, smem + 32768, acc);

    int tid = threadIdx.x;
    int wave = tid >> 6, lane = tid & 63;
    int wm = wave >> 1, wn = wave & 1;
    int g = lane >> 4, c = lane & 15;
    int mbase = m0 + wm * 32, nbase = n0 + wn * 96;
    #pragma unroll
    for (int mt = 0; mt < 2; ++mt) {
        #pragma unroll
        for (int nt = 0; nt < 6; ++nt) {
            f32x4 a = acc[mt][nt];
            int n = nbase + nt * 16 + c;
            int s = n >> 10;            // 0=q 1=k 2=v
            int h = (n >> 6) & 15;
            int d = n & 63;
            float bn = bias[n];
            #pragma unroll
            for (int r = 0; r < 4; ++r) {
                int m = mbase + mt * 16 + g * 4 + r;
                int bb = m >> 11, t = m & 2047;
                float val = a[r] + bn;
                float partner = __shfl_xor(val, 1);
                int bh = bb * 16 + h;
                if (s == 2) {
                    vt[((size_t)bh * 64 + d) * 2048 + t] = f2bf(val);
                } else {
                    int i2 = d >> 1;
                    float2 cs = tab[t * 32 + i2];
                    float outv; int dout;
                    if ((d & 1) == 0) { outv = val * cs.x - partner * cs.y; dout = i2; }
                    else              { outv = partner * cs.y + val * cs.x; dout = 32 + i2; }
                    if (s == 0) outv *= SCL;
                    (s == 0 ? q : k)[((size_t)bh * 2048 + t) * 64 + dout] = f2bf(outv);
                }
            }
        }
    }
}

// ---------------- flash attention: swapped-operand 32x32, SPLIT-KV 8-wave blocks ----------------
// Waves 0-3: j in [0,1024); waves 4-7: j in [1024,2048) for the SAME 128 q-rows.
// __launch_bounds__(512, 2): 256-VGPR budget (512,4 forced a 128-reg cap -> spill).
__global__ __launch_bounds__(512, 2) void attn_kernel(
    const unsigned short* __restrict__ Q, const unsigned short* __restrict__ Kin,
    const unsigned short* __restrict__ VT, unsigned short* __restrict__ O) {
    __shared__ int4 smem4[65536 / 16];     // 64 KB
    char* smem = (char*)smem4;
    const int T = 2048, NT = 16;           // 16 tiles of 64 j per half
    int flat = blockIdx.x + 16 * blockIdx.y;
    int swzb = (flat & 7) * 64 + (flat >> 3);
    int bh = swzb >> 4;
    int qt = swzb & 15;
    int tid = threadIdx.x, wave = tid >> 6, lane = tid & 63;
    int lam = lane & 31, hi = lane >> 5;
    int pair = wave & 3, half = wave >> 2;
    int q = qt * 128 + pair * 32 + lam;

    const unsigned short* Qb = Q + ((size_t)bh * T + q) * 64;
    const unsigned short* Kb = Kin + (size_t)bh * T * 64;
    const unsigned short* VTb = VT + (size_t)bh * 64 * T;

    // Q fragments: load + pin in prologue (keeps the loads out of the loop).
    uint32x4 qtmp[4];
    #pragma unroll
    for (int c4 = 0; c4 < 4; ++c4)
        qtmp[c4] = *reinterpret_cast<const uint32x4*>(Qb + c4 * 16 + hi * 8);
    #pragma unroll
    for (int c4 = 0; c4 < 4; ++c4)
        asm volatile("" : "+v"(qtmp[c4]));
    short8 qf[4];
    #pragma unroll
    for (int c4 = 0; c4 < 4; ++c4) qf[c4] = __builtin_bit_cast(short8, qtmp[c4]);

    short8 ones;
    #pragma unroll
    for (int i = 0; i < 8; ++i) ones[i] = (short)0x3F80;   // bf16 1.0

    f32x16 o0 = zero16(), o1 = zero16(), lacc = zero16();
    float m_run = -1e30f;
    int swz = (lam & 7) << 4;

    // this half's LDS: [buf0|buf1] 8KB each
    char* Ks0 = smem + half * 16384;
    char* Vs0 = smem + 32768 + half * 16384;

    // staging: 4 waves of a half fill its 8KB K-tile + 8KB V-tile (4 loads/wave)
    auto stage = [&](int buf, int t) {
        int j0 = half * 1024 + t * 64;
        #pragma unroll
        for (int i = 0; i < 2; ++i) {
            int call = pair * 2 + i;           // 0..7
            int s = call * 64 + lane;
            int row = s >> 3, c8 = s & 7;
            int csw = (c8 ^ (row & 7)) << 3;
            gload_lds16(Kb + (size_t)(j0 + row) * 64 + csw,
                        Ks0 + buf * 8192 + call * 1024, lane);
            gload_lds16(VTb + (size_t)row * T + j0 + csw,
                        Vs0 + buf * 8192 + call * 1024, lane);
        }
    };

    stage(0, 0);     // prologue: tile 0 in flight

    #pragma unroll 1
    for (int t = 0; t < NT; ++t) {
        int cur = t & 1;
        // my tile-t loads done (one full compute phase in flight)
        asm volatile("s_waitcnt vmcnt(0)" ::: "memory");
        __builtin_amdgcn_s_barrier();
        __builtin_amdgcn_sched_barrier(0);
        if (t + 1 < NT) stage(cur ^ 1, t + 1);   // in flight across compute

        const char* Kc = Ks0 + cur * 8192;
        const char* Vc = Vs0 + cur * 8192;

        // ---- S^T = K Q^T over d-chunks of 16 ----
        f32x16 s0 = zero16(), s1 = zero16();
        __builtin_amdgcn_s_setprio(1);
        #pragma unroll
        for (int c4 = 0; c4 < 4; ++c4) {
            int col = c4 * 32 + hi * 16;
            short8 kf0 = *reinterpret_cast<const short8*>(Kc + ((lam * 128 + col) ^ swz));
            s0 = mfma32(kf0, qf[c4], s0);
            short8 kf1 = *reinterpret_cast<const short8*>(Kc + (((lam + 32) * 128 + col) ^ swz));
            s1 = mfma32(kf1, qf[c4], s1);
        }
        __builtin_amdgcn_s_setprio(0);

        // ---- online softmax (scale pre-folded into q); max3-fusable chain; defer THR=8 ----
        float tm = fmaxf(s0[0], s1[0]);
        #pragma unroll
        for (int r = 1; r < 16; ++r) tm = fmaxf(tm, fmaxf(s0[r], s1[r]));
        float tmax = red_max32(tm);
        if (__any(tmax - m_run > 8.0f)) {
            float mnew = fmaxf(m_run, tmax);
            float alpha = exp2f(m_run - mnew);
            m_run = mnew;
            #pragma unroll
            for (int r = 0; r < 16; ++r) {
                o0[r] *= alpha; o1[r] *= alpha; lacc[r] *= alpha;
            }
        }
        float p0[16], p1[16];
        #pragma unroll
        for (int r = 0; r < 16; ++r) p0[r] = exp2f(s0[r] - m_run);
        #pragma unroll
        for (int r = 0; r < 16; ++r) p1[r] = exp2f(s1[r] - m_run);

        // ---- P -> bf16 A-frags: cvt_pk + permlane32_swap cross-half exchange ----
        short8 pa[4];
        #pragma unroll
        for (int blk = 0; blk < 2; ++blk) {
            const float* p = blk ? p1 : p0;
            #pragma unroll
            for (int jt = 0; jt < 2; ++jt) {
                unsigned a0 = cvt_pk_bf16(p[jt * 8 + 0], p[jt * 8 + 1]);
                unsigned a1 = cvt_pk_bf16(p[jt * 8 + 2], p[jt * 8 + 3]);
                unsigned b0 = cvt_pk_bf16(p[jt * 8 + 4], p[jt * 8 + 5]);
                unsigned b1 = cvt_pk_bf16(p[jt * 8 + 6], p[jt * 8 + 7]);
                uint2 pr0 = permswap(a0, b0);
                uint2 pr1 = permswap(a1, b1);
                uint4 w;
                w.x = pr0.x;
                w.y = pr1.x;
                w.z = pr0.y;
                w.w = pr1.y;
                pa[blk * 2 + jt] = __builtin_bit_cast(short8, w);
            }
        }

        // ---- O^T += V^T P (+ l via ones-MFMA): d on reg-rows, q on lanes ----
        __builtin_amdgcn_s_setprio(1);
        #pragma unroll
        for (int jt = 0; jt < 4; ++jt) {
            int col = jt * 32 + hi * 16;
            short8 vf0 = *reinterpret_cast<const short8*>(Vc + ((lam * 128 + col) ^ swz));
            o0 = mfma32(vf0, pa[jt], o0);
            short8 vf1 = *reinterpret_cast<const short8*>(Vc + (((lam + 32) * 128 + col) ^ swz));
            o1 = mfma32(vf1, pa[jt], o1);
            lacc = mfma32(ones, pa[jt], lacc);
        }
        __builtin_amdgcn_s_setprio(0);
    }

    float l_run = lacc[0];

    // ---- split-KV merge: upper-half waves publish (o, m, l); lower-half merges ----
    __syncthreads();
    float* pb = (float*)(smem + pair * 8704);   // [64 lanes][34 f32]
    if (half) {
        #pragma unroll
        for (int r = 0; r < 16; ++r) {
            pb[lane * 34 + r] = o0[r];
            pb[lane * 34 + 16 + r] = o1[r];
        }
        pb[lane * 34 + 32] = m_run;
        pb[lane * 34 + 33] = l_run;
    }
    __syncthreads();
    if (half) return;

    float mb = pb[lane * 34 + 32], lb = pb[lane * 34 + 33];
    float m = fmaxf(m_run, mb);
    float wa = exp2f(m_run - m), wb = exp2f(mb - m);
    float l = l_run * wa + lb * wb;
    float rinv = 1.0f / l;
    #pragma unroll
    for (int r = 0; r < 16; ++r) {
        o0[r] = o0[r] * wa + pb[lane * 34 + r] * wb;
        o1[r] = o1[r] * wa + pb[lane * 34 + 16 + r] * wb;
    }

    // ---- epilogue: O[q][d] = o[d-reg][q] / l ; write [B][T][H*64] ----
    int b_ = bh >> 4, h_ = bh & 15;
    unsigned short* Orow = O + ((size_t)(b_ * 2048) + q) * 1024 + h_ * 64;
    #pragma unroll
    for (int rq = 0; rq < 4; ++rq) {
        ushort4 w0, w1;
        w0.x = f2bf(o0[rq * 4 + 0] * rinv);
        w0.y = f2bf(o0[rq * 4 + 1] * rinv);
        w0.z = f2bf(o0[rq * 4 + 2] * rinv);
        w0.w = f2bf(o0[rq * 4 + 3] * rinv);
        w1.x = f2bf(o1[rq * 4 + 0] * rinv);
        w1.y = f2bf(o1[rq * 4 + 1] * rinv);
        w1.z = f2bf(o1[rq * 4 + 2] * rinv);
        w1.w = f2bf(o1[rq * 4 + 3] * rinv);
        int d0 = rq * 8 + hi * 4;
        *reinterpret_cast<ushort4*>(Orow + d0) = w0;
        *reinterpret_cast<ushort4*>(Orow + 32 + d0) = w1;
    }
}

// ---------------- output GEMM (64x128 tile, grid 512 -> 2 blocks/CU) + bias, fp32 out ----------------
__global__ __launch_bounds__(512, 2) void out_gemm_kernel(
    const unsigned short* __restrict__ Aattn, const unsigned short* __restrict__ W,
    const float* __restrict__ bias, float* __restrict__ out) {
    __shared__ char smem[48 * 1024];    // A dbuf 16K + B dbuf 32K
    const int K = 1024, N = 1024;
    // XCD swizzle, nwg=512: consecutive swzb within an XCD share the B n-panel
    int flat = blockIdx.x;
    int swzb = (flat & 7) * 64 + (flat >> 3);
    int m0 = (swzb & 63) * 64, n0 = (swzb >> 6) * 128;
    f32x4 acc[2][2];
    #pragma unroll
    for (int i = 0; i < 2; ++i)
        #pragma unroll
        for (int j = 0; j < 2; ++j) acc[i][j] = zero4();

    gemm_mainloop<64, 128, 2, 4>(Aattn, W, K, m0, n0, smem, smem + 16384, acc);

    int tid = threadIdx.x;
    int wave = tid >> 6, lane = tid & 63;
    int wm = wave >> 2, wn = wave & 3;
    int g = lane >> 4, c = lane & 15;
    int mbase = m0 + wm * 32, nbase = n0 + wn * 32;
    #pragma unroll
    for (int mt = 0; mt < 2; ++mt)
        #pragma unroll
        for (int nt = 0; nt < 2; ++nt) {
            int n = nbase + nt * 16 + c;
            float bn = bias[n];
            #pragma unroll
            for (int r = 0; r < 4; ++r) {
                int m = mbase + mt * 16 + g * 4 + r;
                out[(size_t)m * N + n] = acc[mt][nt][r] + bn;
            }
        }
}

extern "C" void kernel_launch(void* const* d_in, const int* in_sizes, int n_in,
                              void* d_out, int out_size, void* d_ws, size_t ws_size,
                              hipStream_t stream) {
    (void)in_sizes; (void)n_in; (void)out_size; (void)ws_size;
    const float* x     = (const float*)d_in[0];
    const float* w_qkv = (const float*)d_in[1];
    const float* b_qkv = (const float*)d_in[2];
    const float* w_out = (const float*)d_in[3];
    const float* b_out = (const float*)d_in[4];
    float* out = (float*)d_out;

    const int B = 2, T = 2048, D = 1024;
    const int M = B * T;                 // 4096
    const size_t MB = 1024 * 1024;
    (void)D; (void)M;

    char* ws = (char*)d_ws;
    unsigned short* xb    = (unsigned short*)(ws);            // 8 MB  x bf16 [4096][1024]
    unsigned short* wqkvb = (unsigned short*)(ws + 8 * MB);   // 6 MB  w_qkv bf16
    unsigned short* woutb = (unsigned short*)(ws + 14 * MB);  // 2 MB  w_out bf16
    unsigned short* qb    = (unsigned short*)(ws + 16 * MB);  // 8 MB  q (pre-scaled) [32][2048][64]
    unsigned short* kb    = (unsigned short*)(ws + 24 * MB);  // 8 MB  k
    unsigned short* vtb   = (unsigned short*)(ws + 32 * MB);  // 8 MB  v^T [32][64][2048]
    unsigned short* attnb = (unsigned short*)(ws + 40 * MB);  // 8 MB  attn out [4096][1024]
    float2* tab           = (float2*)(ws + 48 * MB);          // 512 KB rope table

    prep_kernel<<<dim3((2097152 + 65536) / 256), dim3(256), 0, stream>>>(
        x, w_qkv, w_out, xb, wqkvb, woutb, tab);
    qkv_gemm_kernel<<<dim3(512), dim3(512), 0, stream>>>(xb, wqkvb, b_qkv, tab, qb, kb, vtb);
    attn_kernel<<<dim3(T / 128, B * 16), dim3(512), 0, stream>>>(qb, kb, vtb, attnb);
    out_gemm_kernel<<<dim3(512), dim3(512), 0, stream>>>(attnb, woutb, b_out, out);
}

// Round 14
// 140.133 us; speedup vs baseline: 1.2387x; 1.0271x over previous
//
#include <hip/hip_runtime.h>
#include <cstdint>
#include <cstddef>

typedef __attribute__((ext_vector_type(8))) short short8;
typedef __attribute__((ext_vector_type(8))) __bf16 bf16x8;
typedef __attribute__((ext_vector_type(4))) float f32x4;
typedef __attribute__((ext_vector_type(16))) float f32x16;
typedef __attribute__((ext_vector_type(4))) unsigned int uint32x4;

#define LOG2E 1.44269504088896340736f

__device__ __forceinline__ unsigned short f2bf(float f) {
    unsigned int u = __builtin_bit_cast(unsigned int, f);
    u += 0x7fffu + ((u >> 16) & 1u);
    return (unsigned short)(u >> 16);
}

__device__ __forceinline__ f32x4 zero4() {
    f32x4 z; z.x = 0.f; z.y = 0.f; z.z = 0.f; z.w = 0.f; return z;
}
__device__ __forceinline__ f32x16 zero16() {
    f32x16 z;
    #pragma unroll
    for (int i = 0; i < 16; ++i) z[i] = 0.f;
    return z;
}

__device__ __forceinline__ f32x4 mfma16(short8 a, short8 b, f32x4 c) {
    return __builtin_amdgcn_mfma_f32_16x16x32_bf16(
        __builtin_bit_cast(bf16x8, a), __builtin_bit_cast(bf16x8, b), c, 0, 0, 0);
}
__device__ __forceinline__ f32x16 mfma32(short8 a, short8 b, f32x16 c) {
    return __builtin_amdgcn_mfma_f32_32x32x16_bf16(
        __builtin_bit_cast(bf16x8, a), __builtin_bit_cast(bf16x8, b), c, 0, 0, 0);
}

__device__ __forceinline__ unsigned int cvt_pk_bf16(float lo, float hi) {
    unsigned int r;
    asm("v_cvt_pk_bf16_f32 %0, %1, %2" : "=v"(r) : "v"(lo), "v"(hi));
    return r;
}

// v_permlane32_swap_b32 (CDNA4 ISA): for l in 0..31: vdst[l+32] <-> vsrc[l].
// ret.x (new vdst): lanes<32 = x[l],    lanes>=32 = y[l-32]
// ret.y (new vsrc): lanes<32 = x[l+32], lanes>=32 = y[l]
__device__ __forceinline__ uint2 permswap(unsigned x, unsigned y) {
#if __has_builtin(__builtin_amdgcn_permlane32_swap)
    auto r = __builtin_amdgcn_permlane32_swap(x, y, false, false);
    return make_uint2(r[0], r[1]);
#else
    int lane = threadIdx.x & 63;
    unsigned sy = __shfl_xor(y, 32), sx = __shfl_xor(x, 32);
    return make_uint2((lane < 32) ? x : sy, (lane < 32) ? sx : y);
#endif
}
__device__ __forceinline__ float red_max32(float v) {
    unsigned u = __builtin_bit_cast(unsigned, v);
    uint2 p = permswap(u, u);
    return fmaxf(__builtin_bit_cast(float, p.x), __builtin_bit_cast(float, p.y));
}

// async 16B global->LDS: per-lane g, wave-uniform lds base l; HW writes l + lane*16
__device__ __forceinline__ void gload_lds16(const void* g, void* l, int lane) {
#if __has_builtin(__builtin_amdgcn_global_load_lds)
    __builtin_amdgcn_global_load_lds(
        (const __attribute__((address_space(1))) void*)g,
        (__attribute__((address_space(3))) void*)l, 16, 0, 0);
    (void)lane;
#else
    reinterpret_cast<int4*>(l)[lane] = *reinterpret_cast<const int4*>(g);
#endif
}

// ---------------- fused prep: 3x fp32->bf16 cast + RoPE table ----------------
__global__ __launch_bounds__(256) void prep_kernel(
    const float* __restrict__ x, const float* __restrict__ wq,
    const float* __restrict__ wo,
    unsigned short* __restrict__ xb, unsigned short* __restrict__ wqb,
    unsigned short* __restrict__ wob, float2* __restrict__ tab) {
    const int S0 = 1048576, S1 = 786432, S2 = 262144;   // float4 counts
    int i = blockIdx.x * 256 + threadIdx.x;
    const float* src; unsigned short* dst; int j;
    if (i < S0) { src = x; dst = xb; j = i; }
    else if (i < S0 + S1) { src = wq; dst = wqb; j = i - S0; }
    else if (i < S0 + S1 + S2) { src = wo; dst = wob; j = i - S0 - S1; }
    else {
        int idx = i - (S0 + S1 + S2);
        if (idx < 2048 * 32) {
            int t = idx >> 5, ii = idx & 31;
            float inv_freq = powf(10000.0f, -(float)ii / 32.0f);
            float ang = (float)t * inv_freq;
            tab[idx] = make_float2(cosf(ang), sinf(ang));
        }
        return;
    }
    float4 v = reinterpret_cast<const float4*>(src)[j];
    ushort4 o;
    o.x = f2bf(v.x); o.y = f2bf(v.y); o.z = f2bf(v.z); o.w = f2bf(v.w);
    reinterpret_cast<ushort4*>(dst)[j] = o;
}

// ---------------- templated NT bf16 GEMM mainloop (BK=64), double-buffered ----------------
// 8 waves (512 thr) as WMG x WNG wave grid; per-wave sub-tile (BM/WMG) x (BN/WNG).
// 2 blocks/CU = 16 waves/CU = 4/SIMD.
template<int BM, int BN, int WMG, int WNG>
__device__ __forceinline__ void gemm_mainloop(
    const unsigned short* __restrict__ A, const unsigned short* __restrict__ B,
    int K, int m0, int n0, char* As, char* Bs,
    f32x4 (&acc)[BM / (WMG * 16)][BN / (WNG * 16)]) {
    constexpr int MT = BM / (WMG * 16), NTT = BN / (WNG * 16);
    constexpr int CA = BM / 64, CB = BN / 64;        // 16B chunks per thread
    constexpr int ABUF = BM * 128, BBUF = BN * 128;  // bytes per buffer
    int tid = threadIdx.x;
    int wave = tid >> 6, lane = tid & 63;
    int wm = wave / WNG, wn = wave % WNG;
    int g = lane >> 4, c = lane & 15;
    const int NS = K >> 6;

    auto stage = [&](int buf, int k0) {
        #pragma unroll
        for (int i = 0; i < CA; ++i) {
            int call = wave * CA + i;
            int s = call * 64 + lane;
            int row = s >> 3, c8 = s & 7;
            int csw = (c8 ^ (row & 7)) << 3;
            gload_lds16(A + (size_t)(m0 + row) * K + k0 + csw,
                        As + buf * ABUF + call * 1024, lane);
        }
        #pragma unroll
        for (int i = 0; i < CB; ++i) {
            int call = wave * CB + i;
            int s = call * 64 + lane;
            int row = s >> 3, c8 = s & 7;
            int csw = (c8 ^ (row & 7)) << 3;
            gload_lds16(B + (size_t)(n0 + row) * K + k0 + csw,
                        Bs + buf * BBUF + call * 1024, lane);
        }
    };

    stage(0, 0);   // tile 0 in flight

    #pragma unroll 1
    for (int t = 0; t < NS; ++t) {
        int cur = t & 1;
        asm volatile("s_waitcnt vmcnt(0)" ::: "memory");
        __builtin_amdgcn_s_barrier();    // all waves' tile-t resident; buf[cur^1] free
        __builtin_amdgcn_sched_barrier(0);
        if (t + 1 < NS) stage(cur ^ 1, (t + 1) * 64);   // in flight across compute

        const char* Ac = As + cur * ABUF;
        const char* Bc = Bs + cur * BBUF;
        #pragma unroll
        for (int kg = 0; kg < 2; ++kg) {
            short8 af[MT], bfr[NTT];
            #pragma unroll
            for (int mt = 0; mt < MT; ++mt) {
                int row = wm * (BM / WMG) + mt * 16 + c;
                af[mt] = *reinterpret_cast<const short8*>(Ac +
                    ((row * 128 + kg * 64 + g * 16) ^ ((row & 7) << 4)));
            }
            #pragma unroll
            for (int nt = 0; nt < NTT; ++nt) {
                int row = wn * (BN / WNG) + nt * 16 + c;
                bfr[nt] = *reinterpret_cast<const short8*>(Bc +
                    ((row * 128 + kg * 64 + g * 16) ^ ((row & 7) << 4)));
            }
            __builtin_amdgcn_s_setprio(1);
            #pragma unroll
            for (int mt = 0; mt < MT; ++mt)
                #pragma unroll
                for (int nt = 0; nt < NTT; ++nt)
                    acc[mt][nt] = mfma16(af[mt], bfr[nt], acc[mt][nt]);
            __builtin_amdgcn_s_setprio(0);
        }
    }
}

// ---------------- QKV GEMM (128x192 tile, grid 512 = one full generation) ----------------
// + bias + RoPE; q (pre-scaled by 0.125*log2e), k -> [B*H][T][64], v -> [B*H][64][T]
__global__ __launch_bounds__(512, 2) void qkv_gemm_kernel(
    const unsigned short* __restrict__ X, const unsigned short* __restrict__ W,
    const float* __restrict__ bias, const float2* __restrict__ tab,
    unsigned short* __restrict__ q, unsigned short* __restrict__ k,
    unsigned short* __restrict__ vt) {
    __shared__ char smem[80 * 1024];     // A dbuf 32K + B dbuf 48K
    const int K = 1024;
    const float SCL = 0.125f * LOG2E;    // folded into q
    int flat = blockIdx.x;
    int swzb = (flat & 7) * 64 + (flat >> 3);
    int m0 = (swzb >> 4) * 128, n0 = (swzb & 15) * 192;
    f32x4 acc[2][6];
    #pragma unroll
    for (int i = 0; i < 2; ++i)
        #pragma unroll
        for (int j = 0; j < 6; ++j) acc[i][j] = zero4();

    gemm_mainloop<128, 192, 4, 2>(X, W, K, m0, n0, smem, smem + 32768, acc);

    int tid = threadIdx.x;
    int wave = tid >> 6, lane = tid & 63;
    int wm = wave >> 1, wn = wave & 1;
    int g = lane >> 4, c = lane & 15;
    int mbase = m0 + wm * 32, nbase = n0 + wn * 96;
    #pragma unroll
    for (int mt = 0; mt < 2; ++mt) {
        #pragma unroll
        for (int nt = 0; nt < 6; ++nt) {
            f32x4 a = acc[mt][nt];
            int n = nbase + nt * 16 + c;
            int s = n >> 10;            // 0=q 1=k 2=v
            int h = (n >> 6) & 15;
            int d = n & 63;
            float bn = bias[n];
            #pragma unroll
            for (int r = 0; r < 4; ++r) {
                int m = mbase + mt * 16 + g * 4 + r;
                int bb = m >> 11, t = m & 2047;
                float val = a[r] + bn;
                float partner = __shfl_xor(val, 1);
                int bh = bb * 16 + h;
                if (s == 2) {
                    vt[((size_t)bh * 64 + d) * 2048 + t] = f2bf(val);
                } else {
                    int i2 = d >> 1;
                    float2 cs = tab[t * 32 + i2];
                    float outv; int dout;
                    if ((d & 1) == 0) { outv = val * cs.x - partner * cs.y; dout = i2; }
                    else              { outv = partner * cs.y + val * cs.x; dout = 32 + i2; }
                    if (s == 0) outv *= SCL;
                    (s == 0 ? q : k)[((size_t)bh * 2048 + t) * 64 + dout] = f2bf(outv);
                }
            }
        }
    }
}

// ---------------- flash attention: swapped-operand 32x32, KVBLK=128 (2x64 sub-tiles) ----------------
// 4-wave (256-thr) blocks, each wave owns 32 q-rows; all waves share the K/V tiles.
// One vmcnt+barrier+stage stop per 128 j (was per 64 j) — halves the per-stop
// 2-phase overhead (m233) per FLOP. 2 independent blocks/CU drift in phase.
// ROUND-13 BUG FIX: NT = 16 (16 tiles x 128 j = 2048 = full context; NT=8 only
// covered half the keys -> absmax 5e-2).
__global__ __launch_bounds__(256, 2) void attn_kernel(
    const unsigned short* __restrict__ Q, const unsigned short* __restrict__ Kin,
    const unsigned short* __restrict__ VT, unsigned short* __restrict__ O) {
    __shared__ int4 smem4[65536 / 16];     // 64 KB: K dbuf 32K + V dbuf 32K
    char* smem = (char*)smem4;
    const int T = 2048, NT = 16;           // 16 tiles of 128 j = full 2048 context
    int flat = blockIdx.x + 16 * blockIdx.y;
    int swzb = (flat & 7) * 64 + (flat >> 3);
    int bh = swzb >> 4;
    int qt = swzb & 15;
    int tid = threadIdx.x, wave = tid >> 6, lane = tid & 63;
    int lam = lane & 31, hi = lane >> 5;
    int q = qt * 128 + wave * 32 + lam;

    const unsigned short* Qb = Q + ((size_t)bh * T + q) * 64;
    const unsigned short* Kb = Kin + (size_t)bh * T * 64;
    const unsigned short* VTb = VT + (size_t)bh * 64 * T;

    // Q fragments: load + pin in prologue (keeps the loads out of the loop).
    uint32x4 qtmp[4];
    #pragma unroll
    for (int c4 = 0; c4 < 4; ++c4)
        qtmp[c4] = *reinterpret_cast<const uint32x4*>(Qb + c4 * 16 + hi * 8);
    #pragma unroll
    for (int c4 = 0; c4 < 4; ++c4)
        asm volatile("" : "+v"(qtmp[c4]));
    short8 qf[4];
    #pragma unroll
    for (int c4 = 0; c4 < 4; ++c4) qf[c4] = __builtin_bit_cast(short8, qtmp[c4]);

    short8 ones;
    #pragma unroll
    for (int i = 0; i < 8; ++i) ones[i] = (short)0x3F80;   // bf16 1.0

    f32x16 o0 = zero16(), o1 = zero16(), lacc = zero16();
    float m_run = -1e30f;
    int swz = (lam & 7) << 4;

    char* KsB = smem;            // [2][16KB] = [2][2 sub-tiles][8KB]
    char* VsB = smem + 32768;    // [2][16KB]

    // staging: 4 waves fill a 16KB K-tile + 16KB V-tile (8 loads/wave):
    // two contiguous 64-j sub-tiles, each with the round-8 layout + swizzle.
    auto stage = [&](int buf, int t) {
        int j0 = t * 128;
        #pragma unroll
        for (int st = 0; st < 2; ++st) {
            #pragma unroll
            for (int i = 0; i < 2; ++i) {
                int call = wave * 2 + i;           // 0..7
                int s = call * 64 + lane;          // 0..511
                int row = s >> 3, c8 = s & 7;
                int csw = (c8 ^ (row & 7)) << 3;
                gload_lds16(Kb + (size_t)(j0 + st * 64 + row) * 64 + csw,
                            KsB + buf * 16384 + st * 8192 + call * 1024, lane);
                gload_lds16(VTb + (size_t)row * T + j0 + st * 64 + csw,
                            VsB + buf * 16384 + st * 8192 + call * 1024, lane);
            }
        }
    };

    // per-64-j sub-tile compute (identical to the verified round-8 body)
    auto subtile = [&](const char* Kc, const char* Vc) {
        // ---- S^T = K Q^T over d-chunks of 16 ----
        f32x16 s0 = zero16(), s1 = zero16();
        __builtin_amdgcn_s_setprio(1);
        #pragma unroll
        for (int c4 = 0; c4 < 4; ++c4) {
            int col = c4 * 32 + hi * 16;
            short8 kf0 = *reinterpret_cast<const short8*>(Kc + ((lam * 128 + col) ^ swz));
            s0 = mfma32(kf0, qf[c4], s0);
            short8 kf1 = *reinterpret_cast<const short8*>(Kc + (((lam + 32) * 128 + col) ^ swz));
            s1 = mfma32(kf1, qf[c4], s1);
        }
        __builtin_amdgcn_s_setprio(0);

        // ---- online softmax (scale pre-folded into q); defer-max THR=8 ----
        float tm = fmaxf(s0[0], s1[0]);
        #pragma unroll
        for (int r = 1; r < 16; ++r) tm = fmaxf(tm, fmaxf(s0[r], s1[r]));
        float tmax = red_max32(tm);
        if (__any(tmax - m_run > 8.0f)) {
            float mnew = fmaxf(m_run, tmax);
            float alpha = exp2f(m_run - mnew);
            m_run = mnew;
            #pragma unroll
            for (int r = 0; r < 16; ++r) {
                o0[r] *= alpha; o1[r] *= alpha; lacc[r] *= alpha;
            }
        }
        float p0[16], p1[16];
        #pragma unroll
        for (int r = 0; r < 16; ++r) p0[r] = exp2f(s0[r] - m_run);
        #pragma unroll
        for (int r = 0; r < 16; ++r) p1[r] = exp2f(s1[r] - m_run);

        // ---- P -> bf16 A-frags: cvt_pk + permlane32_swap cross-half exchange ----
        short8 pa[4];
        #pragma unroll
        for (int blk = 0; blk < 2; ++blk) {
            const float* p = blk ? p1 : p0;
            #pragma unroll
            for (int jt = 0; jt < 2; ++jt) {
                unsigned a0 = cvt_pk_bf16(p[jt * 8 + 0], p[jt * 8 + 1]);
                unsigned a1 = cvt_pk_bf16(p[jt * 8 + 2], p[jt * 8 + 3]);
                unsigned b0 = cvt_pk_bf16(p[jt * 8 + 4], p[jt * 8 + 5]);
                unsigned b1 = cvt_pk_bf16(p[jt * 8 + 6], p[jt * 8 + 7]);
                uint2 pr0 = permswap(a0, b0);
                uint2 pr1 = permswap(a1, b1);
                uint4 w;
                w.x = pr0.x;
                w.y = pr1.x;
                w.z = pr0.y;
                w.w = pr1.y;
                pa[blk * 2 + jt] = __builtin_bit_cast(short8, w);
            }
        }

        // ---- O^T += V^T P (+ l via ones-MFMA): d on reg-rows, q on lanes ----
        __builtin_amdgcn_s_setprio(1);
        #pragma unroll
        for (int jt = 0; jt < 4; ++jt) {
            int col = jt * 32 + hi * 16;
            short8 vf0 = *reinterpret_cast<const short8*>(Vc + ((lam * 128 + col) ^ swz));
            o0 = mfma32(vf0, pa[jt], o0);
            short8 vf1 = *reinterpret_cast<const short8*>(Vc + (((lam + 32) * 128 + col) ^ swz));
            o1 = mfma32(vf1, pa[jt], o1);
            lacc = mfma32(ones, pa[jt], lacc);
        }
        __builtin_amdgcn_s_setprio(0);
    };

    stage(0, 0);     // prologue: tile 0 in flight

    #pragma unroll 1
    for (int t = 0; t < NT; ++t) {
        int cur = t & 1;
        // my tile-t loads done (one full 128-j compute phase in flight)
        asm volatile("s_waitcnt vmcnt(0)" ::: "memory");
        __builtin_amdgcn_s_barrier();
        __builtin_amdgcn_sched_barrier(0);
        if (t + 1 < NT) stage(cur ^ 1, t + 1);   // in flight across compute

        subtile(KsB + cur * 16384, VsB + cur * 16384);
        subtile(KsB + cur * 16384 + 8192, VsB + cur * 16384 + 8192);
    }

    float l_run = lacc[0];

    // ---- epilogue: O[q][d] = o[d-reg][q] / l ; write [B][T][H*64] ----
    float rinv = 1.0f / l_run;
    int b_ = bh >> 4, h_ = bh & 15;
    unsigned short* Orow = O + ((size_t)(b_ * 2048) + q) * 1024 + h_ * 64;
    #pragma unroll
    for (int rq = 0; rq < 4; ++rq) {
        ushort4 w0, w1;
        w0.x = f2bf(o0[rq * 4 + 0] * rinv);
        w0.y = f2bf(o0[rq * 4 + 1] * rinv);
        w0.z = f2bf(o0[rq * 4 + 2] * rinv);
        w0.w = f2bf(o0[rq * 4 + 3] * rinv);
        w1.x = f2bf(o1[rq * 4 + 0] * rinv);
        w1.y = f2bf(o1[rq * 4 + 1] * rinv);
        w1.z = f2bf(o1[rq * 4 + 2] * rinv);
        w1.w = f2bf(o1[rq * 4 + 3] * rinv);
        int d0 = rq * 8 + hi * 4;
        *reinterpret_cast<ushort4*>(Orow + d0) = w0;
        *reinterpret_cast<ushort4*>(Orow + 32 + d0) = w1;
    }
}

// ---------------- output GEMM (64x128 tile, grid 512 -> 2 blocks/CU) + bias, fp32 out ----------------
__global__ __launch_bounds__(512, 2) void out_gemm_kernel(
    const unsigned short* __restrict__ Aattn, const unsigned short* __restrict__ W,
    const float* __restrict__ bias, float* __restrict__ out) {
    __shared__ char smem[48 * 1024];    // A dbuf 16K + B dbuf 32K
    const int K = 1024, N = 1024;
    int flat = blockIdx.x;
    int swzb = (flat & 7) * 64 + (flat >> 3);
    int m0 = (swzb & 63) * 64, n0 = (swzb >> 6) * 128;
    f32x4 acc[2][2];
    #pragma unroll
    for (int i = 0; i < 2; ++i)
        #pragma unroll
        for (int j = 0; j < 2; ++j) acc[i][j] = zero4();

    gemm_mainloop<64, 128, 2, 4>(Aattn, W, K, m0, n0, smem, smem + 16384, acc);

    int tid = threadIdx.x;
    int wave = tid >> 6, lane = tid & 63;
    int wm = wave >> 2, wn = wave & 3;
    int g = lane >> 4, c = lane & 15;
    int mbase = m0 + wm * 32, nbase = n0 + wn * 32;
    #pragma unroll
    for (int mt = 0; mt < 2; ++mt)
        #pragma unroll
        for (int nt = 0; nt < 2; ++nt) {
            int n = nbase + nt * 16 + c;
            float bn = bias[n];
            #pragma unroll
            for (int r = 0; r < 4; ++r) {
                int m = mbase + mt * 16 + g * 4 + r;
                out[(size_t)m * N + n] = acc[mt][nt][r] + bn;
            }
        }
}

extern "C" void kernel_launch(void* const* d_in, const int* in_sizes, int n_in,
                              void* d_out, int out_size, void* d_ws, size_t ws_size,
                              hipStream_t stream) {
    (void)in_sizes; (void)n_in; (void)out_size; (void)ws_size;
    const float* x     = (const float*)d_in[0];
    const float* w_qkv = (const float*)d_in[1];
    const float* b_qkv = (const float*)d_in[2];
    const float* w_out = (const float*)d_in[3];
    const float* b_out = (const float*)d_in[4];
    float* out = (float*)d_out;

    const int B = 2, T = 2048, D = 1024;
    const int M = B * T;                 // 4096
    const size_t MB = 1024 * 1024;
    (void)D; (void)M;

    char* ws = (char*)d_ws;
    unsigned short* xb    = (unsigned short*)(ws);            // 8 MB  x bf16 [4096][1024]
    unsigned short* wqkvb = (unsigned short*)(ws + 8 * MB);   // 6 MB  w_qkv bf16
    unsigned short* woutb = (unsigned short*)(ws + 14 * MB);  // 2 MB  w_out bf16
    unsigned short* qb    = (unsigned short*)(ws + 16 * MB);  // 8 MB  q (pre-scaled) [32][2048][64]
    unsigned short* kb    = (unsigned short*)(ws + 24 * MB);  // 8 MB  k
    unsigned short* vtb   = (unsigned short*)(ws + 32 * MB);  // 8 MB  v^T [32][64][2048]
    unsigned short* attnb = (unsigned short*)(ws + 40 * MB);  // 8 MB  attn out [4096][1024]
    float2* tab           = (float2*)(ws + 48 * MB);          // 512 KB rope table

    prep_kernel<<<dim3((2097152 + 65536) / 256), dim3(256), 0, stream>>>(
        x, w_qkv, w_out, xb, wqkvb, woutb, tab);
    qkv_gemm_kernel<<<dim3(512), dim3(512), 0, stream>>>(xb, wqkvb, b_qkv, tab, qb, kb, vtb);
    attn_kernel<<<dim3(T / 128, B * 16), dim3(256), 0, stream>>>(qb, kb, vtb, attnb);
    out_gemm_kernel<<<dim3(512), dim3(512), 0, stream>>>(attnb, woutb, b_out, out);
}

// Round 15
// 138.792 us; speedup vs baseline: 1.2507x; 1.0097x over previous
//
#include <hip/hip_runtime.h>
#include <cstdint>
#include <cstddef>

typedef __attribute__((ext_vector_type(8))) short short8;
typedef __attribute__((ext_vector_type(8))) __bf16 bf16x8;
typedef __attribute__((ext_vector_type(4))) float f32x4;
typedef __attribute__((ext_vector_type(16))) float f32x16;
typedef __attribute__((ext_vector_type(4))) unsigned int uint32x4;

#define LOG2E 1.44269504088896340736f

__device__ __forceinline__ unsigned short f2bf(float f) {
    unsigned int u = __builtin_bit_cast(unsigned int, f);
    u += 0x7fffu + ((u >> 16) & 1u);
    return (unsigned short)(u >> 16);
}

__device__ __forceinline__ f32x4 zero4() {
    f32x4 z; z.x = 0.f; z.y = 0.f; z.z = 0.f; z.w = 0.f; return z;
}
__device__ __forceinline__ f32x16 zero16() {
    f32x16 z;
    #pragma unroll
    for (int i = 0; i < 16; ++i) z[i] = 0.f;
    return z;
}

__device__ __forceinline__ f32x4 mfma16(short8 a, short8 b, f32x4 c) {
    return __builtin_amdgcn_mfma_f32_16x16x32_bf16(
        __builtin_bit_cast(bf16x8, a), __builtin_bit_cast(bf16x8, b), c, 0, 0, 0);
}
__device__ __forceinline__ f32x16 mfma32(short8 a, short8 b, f32x16 c) {
    return __builtin_amdgcn_mfma_f32_32x32x16_bf16(
        __builtin_bit_cast(bf16x8, a), __builtin_bit_cast(bf16x8, b), c, 0, 0, 0);
}

__device__ __forceinline__ unsigned int cvt_pk_bf16(float lo, float hi) {
    unsigned int r;
    asm("v_cvt_pk_bf16_f32 %0, %1, %2" : "=v"(r) : "v"(lo), "v"(hi));
    return r;
}

// v_permlane32_swap_b32 (CDNA4 ISA): for l in 0..31: vdst[l+32] <-> vsrc[l].
// ret.x (new vdst): lanes<32 = x[l],    lanes>=32 = y[l-32]
// ret.y (new vsrc): lanes<32 = x[l+32], lanes>=32 = y[l]
__device__ __forceinline__ uint2 permswap(unsigned x, unsigned y) {
#if __has_builtin(__builtin_amdgcn_permlane32_swap)
    auto r = __builtin_amdgcn_permlane32_swap(x, y, false, false);
    return make_uint2(r[0], r[1]);
#else
    int lane = threadIdx.x & 63;
    unsigned sy = __shfl_xor(y, 32), sx = __shfl_xor(x, 32);
    return make_uint2((lane < 32) ? x : sy, (lane < 32) ? sx : y);
#endif
}
__device__ __forceinline__ float red_max32(float v) {
    unsigned u = __builtin_bit_cast(unsigned, v);
    uint2 p = permswap(u, u);
    return fmaxf(__builtin_bit_cast(float, p.x), __builtin_bit_cast(float, p.y));
}

// async 16B global->LDS: per-lane g, wave-uniform lds base l; HW writes l + lane*16
__device__ __forceinline__ void gload_lds16(const void* g, void* l, int lane) {
#if __has_builtin(__builtin_amdgcn_global_load_lds)
    __builtin_amdgcn_global_load_lds(
        (const __attribute__((address_space(1))) void*)g,
        (__attribute__((address_space(3))) void*)l, 16, 0, 0);
    (void)lane;
#else
    reinterpret_cast<int4*>(l)[lane] = *reinterpret_cast<const int4*>(g);
#endif
}

// ---------------- fused prep: 3x fp32->bf16 cast + RoPE table ----------------
__global__ __launch_bounds__(256) void prep_kernel(
    const float* __restrict__ x, const float* __restrict__ wq,
    const float* __restrict__ wo,
    unsigned short* __restrict__ xb, unsigned short* __restrict__ wqb,
    unsigned short* __restrict__ wob, float2* __restrict__ tab) {
    const int S0 = 1048576, S1 = 786432, S2 = 262144;   // float4 counts
    int i = blockIdx.x * 256 + threadIdx.x;
    const float* src; unsigned short* dst; int j;
    if (i < S0) { src = x; dst = xb; j = i; }
    else if (i < S0 + S1) { src = wq; dst = wqb; j = i - S0; }
    else if (i < S0 + S1 + S2) { src = wo; dst = wob; j = i - S0 - S1; }
    else {
        int idx = i - (S0 + S1 + S2);
        if (idx < 2048 * 32) {
            int t = idx >> 5, ii = idx & 31;
            float inv_freq = powf(10000.0f, -(float)ii / 32.0f);
            float ang = (float)t * inv_freq;
            tab[idx] = make_float2(cosf(ang), sinf(ang));
        }
        return;
    }
    float4 v = reinterpret_cast<const float4*>(src)[j];
    ushort4 o;
    o.x = f2bf(v.x); o.y = f2bf(v.y); o.z = f2bf(v.z); o.w = f2bf(v.w);
    reinterpret_cast<ushort4*>(dst)[j] = o;
}

// ---------------- templated NT bf16 GEMM mainloop (BK=64), double-buffered ----------------
// 8 waves (512 thr) as WMG x WNG wave grid; per-wave sub-tile (BM/WMG) x (BN/WNG).
// 2 blocks/CU = 16 waves/CU = 4/SIMD.
template<int BM, int BN, int WMG, int WNG>
__device__ __forceinline__ void gemm_mainloop(
    const unsigned short* __restrict__ A, const unsigned short* __restrict__ B,
    int K, int m0, int n0, char* As, char* Bs,
    f32x4 (&acc)[BM / (WMG * 16)][BN / (WNG * 16)]) {
    constexpr int MT = BM / (WMG * 16), NTT = BN / (WNG * 16);
    constexpr int CA = BM / 64, CB = BN / 64;        // 16B chunks per thread
    constexpr int ABUF = BM * 128, BBUF = BN * 128;  // bytes per buffer
    int tid = threadIdx.x;
    int wave = tid >> 6, lane = tid & 63;
    int wm = wave / WNG, wn = wave % WNG;
    int g = lane >> 4, c = lane & 15;
    const int NS = K >> 6;

    auto stage = [&](int buf, int k0) {
        #pragma unroll
        for (int i = 0; i < CA; ++i) {
            int call = wave * CA + i;
            int s = call * 64 + lane;
            int row = s >> 3, c8 = s & 7;
            int csw = (c8 ^ (row & 7)) << 3;
            gload_lds16(A + (size_t)(m0 + row) * K + k0 + csw,
                        As + buf * ABUF + call * 1024, lane);
        }
        #pragma unroll
        for (int i = 0; i < CB; ++i) {
            int call = wave * CB + i;
            int s = call * 64 + lane;
            int row = s >> 3, c8 = s & 7;
            int csw = (c8 ^ (row & 7)) << 3;
            gload_lds16(B + (size_t)(n0 + row) * K + k0 + csw,
                        Bs + buf * BBUF + call * 1024, lane);
        }
    };

    stage(0, 0);   // tile 0 in flight

    #pragma unroll 1
    for (int t = 0; t < NS; ++t) {
        int cur = t & 1;
        asm volatile("s_waitcnt vmcnt(0)" ::: "memory");
        __builtin_amdgcn_s_barrier();    // all waves' tile-t resident; buf[cur^1] free
        __builtin_amdgcn_sched_barrier(0);
        if (t + 1 < NS) stage(cur ^ 1, (t + 1) * 64);   // in flight across compute

        const char* Ac = As + cur * ABUF;
        const char* Bc = Bs + cur * BBUF;
        #pragma unroll
        for (int kg = 0; kg < 2; ++kg) {
            short8 af[MT], bfr[NTT];
            #pragma unroll
            for (int mt = 0; mt < MT; ++mt) {
                int row = wm * (BM / WMG) + mt * 16 + c;
                af[mt] = *reinterpret_cast<const short8*>(Ac +
                    ((row * 128 + kg * 64 + g * 16) ^ ((row & 7) << 4)));
            }
            #pragma unroll
            for (int nt = 0; nt < NTT; ++nt) {
                int row = wn * (BN / WNG) + nt * 16 + c;
                bfr[nt] = *reinterpret_cast<const short8*>(Bc +
                    ((row * 128 + kg * 64 + g * 16) ^ ((row & 7) << 4)));
            }
            __builtin_amdgcn_s_setprio(1);
            #pragma unroll
            for (int mt = 0; mt < MT; ++mt)
                #pragma unroll
                for (int nt = 0; nt < NTT; ++nt)
                    acc[mt][nt] = mfma16(af[mt], bfr[nt], acc[mt][nt]);
            __builtin_amdgcn_s_setprio(0);
        }
    }
}

// ---------------- QKV GEMM (128x192 tile, grid 512 = one full generation) ----------------
// + bias + RoPE; q (pre-scaled by 0.125*log2e), k -> [B*H][T][64], v -> [B*H][64][T]
__global__ __launch_bounds__(512, 2) void qkv_gemm_kernel(
    const unsigned short* __restrict__ X, const unsigned short* __restrict__ W,
    const float* __restrict__ bias, const float2* __restrict__ tab,
    unsigned short* __restrict__ q, unsigned short* __restrict__ k,
    unsigned short* __restrict__ vt) {
    __shared__ char smem[80 * 1024];     // A dbuf 32K + B dbuf 48K
    const int K = 1024;
    const float SCL = 0.125f * LOG2E;    // folded into q
    int flat = blockIdx.x;
    int swzb = (flat & 7) * 64 + (flat >> 3);
    int m0 = (swzb >> 4) * 128, n0 = (swzb & 15) * 192;
    f32x4 acc[2][6];
    #pragma unroll
    for (int i = 0; i < 2; ++i)
        #pragma unroll
        for (int j = 0; j < 6; ++j) acc[i][j] = zero4();

    gemm_mainloop<128, 192, 4, 2>(X, W, K, m0, n0, smem, smem + 32768, acc);

    int tid = threadIdx.x;
    int wave = tid >> 6, lane = tid & 63;
    int wm = wave >> 1, wn = wave & 1;
    int g = lane >> 4, c = lane & 15;
    int mbase = m0 + wm * 32, nbase = n0 + wn * 96;
    #pragma unroll
    for (int mt = 0; mt < 2; ++mt) {
        #pragma unroll
        for (int nt = 0; nt < 6; ++nt) {
            f32x4 a = acc[mt][nt];
            int n = nbase + nt * 16 + c;
            int s = n >> 10;            // 0=q 1=k 2=v
            int h = (n >> 6) & 15;
            int d = n & 63;
            float bn = bias[n];
            #pragma unroll
            for (int r = 0; r < 4; ++r) {
                int m = mbase + mt * 16 + g * 4 + r;
                int bb = m >> 11, t = m & 2047;
                float val = a[r] + bn;
                float partner = __shfl_xor(val, 1);
                int bh = bb * 16 + h;
                if (s == 2) {
                    vt[((size_t)bh * 64 + d) * 2048 + t] = f2bf(val);
                } else {
                    int i2 = d >> 1;
                    float2 cs = tab[t * 32 + i2];
                    float outv; int dout;
                    if ((d & 1) == 0) { outv = val * cs.x - partner * cs.y; dout = i2; }
                    else              { outv = partner * cs.y + val * cs.x; dout = 32 + i2; }
                    if (s == 0) outv *= SCL;
                    (s == 0 ? q : k)[((size_t)bh * 2048 + t) * 64 + dout] = f2bf(outv);
                }
            }
        }
    }
}

// ---------------- flash attention: swapped-operand 32x32, KVBLK=128, single softmax pass ----------------
// 4-wave (256-thr) blocks, each wave owns 32 q-rows; all waves share the K/V tiles.
// Per tile: QK^T for all 128 j (s0..s3) -> hoisted V-sub0 register loads (latency
// hides under softmax) -> ONE max/defer/rescale pass per 128 j -> pa[8] -> PV.
// The rescale branch no longer sits between PV's ds_reads and their uses.
__global__ __launch_bounds__(256, 2) void attn_kernel(
    const unsigned short* __restrict__ Q, const unsigned short* __restrict__ Kin,
    const unsigned short* __restrict__ VT, unsigned short* __restrict__ O) {
    __shared__ int4 smem4[65536 / 16];     // 64 KB: K dbuf 32K + V dbuf 32K
    char* smem = (char*)smem4;
    const int T = 2048, NT = 16;           // 16 tiles of 128 j = full context
    int flat = blockIdx.x + 16 * blockIdx.y;
    int swzb = (flat & 7) * 64 + (flat >> 3);
    int bh = swzb >> 4;
    int qt = swzb & 15;
    int tid = threadIdx.x, wave = tid >> 6, lane = tid & 63;
    int lam = lane & 31, hi = lane >> 5;
    int q = qt * 128 + wave * 32 + lam;

    const unsigned short* Qb = Q + ((size_t)bh * T + q) * 64;
    const unsigned short* Kb = Kin + (size_t)bh * T * 64;
    const unsigned short* VTb = VT + (size_t)bh * 64 * T;

    // Q fragments: load + pin in prologue (keeps the loads out of the loop).
    uint32x4 qtmp[4];
    #pragma unroll
    for (int c4 = 0; c4 < 4; ++c4)
        qtmp[c4] = *reinterpret_cast<const uint32x4*>(Qb + c4 * 16 + hi * 8);
    #pragma unroll
    for (int c4 = 0; c4 < 4; ++c4)
        asm volatile("" : "+v"(qtmp[c4]));
    short8 qf[4];
    #pragma unroll
    for (int c4 = 0; c4 < 4; ++c4) qf[c4] = __builtin_bit_cast(short8, qtmp[c4]);

    short8 ones;
    #pragma unroll
    for (int i = 0; i < 8; ++i) ones[i] = (short)0x3F80;   // bf16 1.0

    f32x16 o0 = zero16(), o1 = zero16(), lacc = zero16();
    float m_run = -1e30f;
    int swz = (lam & 7) << 4;

    char* KsB = smem;            // [2][16KB] = [2][2 sub-tiles][8KB]
    char* VsB = smem + 32768;    // [2][16KB]

    // staging: 4 waves fill a 16KB K-tile + 16KB V-tile (8 loads/wave):
    // two contiguous 64-j sub-tiles, each with the verified round-8 layout+swizzle.
    auto stage = [&](int buf, int t) {
        int j0 = t * 128;
        #pragma unroll
        for (int st = 0; st < 2; ++st) {
            #pragma unroll
            for (int i = 0; i < 2; ++i) {
                int call = wave * 2 + i;           // 0..7
                int s = call * 64 + lane;          // 0..511
                int row = s >> 3, c8 = s & 7;
                int csw = (c8 ^ (row & 7)) << 3;
                gload_lds16(Kb + (size_t)(j0 + st * 64 + row) * 64 + csw,
                            KsB + buf * 16384 + st * 8192 + call * 1024, lane);
                gload_lds16(VTb + (size_t)row * T + j0 + st * 64 + csw,
                            VsB + buf * 16384 + st * 8192 + call * 1024, lane);
            }
        }
    };

    stage(0, 0);     // prologue: tile 0 in flight

    #pragma unroll 1
    for (int t = 0; t < NT; ++t) {
        int cur = t & 1;
        // my tile-t loads done (one full 128-j compute phase in flight)
        asm volatile("s_waitcnt vmcnt(0)" ::: "memory");
        __builtin_amdgcn_s_barrier();
        __builtin_amdgcn_sched_barrier(0);
        if (t + 1 < NT) stage(cur ^ 1, t + 1);   // in flight across compute

        const char* Kc = KsB + cur * 16384;
        const char* Vc = VsB + cur * 16384;

        // ---- QK^T for all 128 j: s0/s1 = sub0 (j 0-63), s2/s3 = sub1 (j 64-127) ----
        f32x16 s0 = zero16(), s1 = zero16(), s2 = zero16(), s3 = zero16();
        __builtin_amdgcn_s_setprio(1);
        #pragma unroll
        for (int c4 = 0; c4 < 4; ++c4) {
            int col = c4 * 32 + hi * 16;
            short8 kf;
            kf = *reinterpret_cast<const short8*>(Kc + ((lam * 128 + col) ^ swz));
            s0 = mfma32(kf, qf[c4], s0);
            kf = *reinterpret_cast<const short8*>(Kc + (((lam + 32) * 128 + col) ^ swz));
            s1 = mfma32(kf, qf[c4], s1);
            kf = *reinterpret_cast<const short8*>(Kc + 8192 + ((lam * 128 + col) ^ swz));
            s2 = mfma32(kf, qf[c4], s2);
            kf = *reinterpret_cast<const short8*>(Kc + 8192 + (((lam + 32) * 128 + col) ^ swz));
            s3 = mfma32(kf, qf[c4], s3);
        }
        __builtin_amdgcn_s_setprio(0);

        // ---- hoist V sub0 fragment loads: latency hides under the softmax phase ----
        short8 vf[8];
        #pragma unroll
        for (int jt = 0; jt < 4; ++jt) {
            int col = jt * 32 + hi * 16;
            vf[jt * 2]     = *reinterpret_cast<const short8*>(Vc + ((lam * 128 + col) ^ swz));
            vf[jt * 2 + 1] = *reinterpret_cast<const short8*>(Vc + (((lam + 32) * 128 + col) ^ swz));
        }

        // ---- ONE softmax pass over 128 j (scale pre-folded into q); defer-max THR=8 ----
        float mx[16];
        #pragma unroll
        for (int r = 0; r < 16; ++r)
            mx[r] = fmaxf(fmaxf(s0[r], s1[r]), fmaxf(s2[r], s3[r]));
        float tm = mx[0];
        #pragma unroll
        for (int r = 1; r < 16; ++r) tm = fmaxf(tm, mx[r]);
        float tmax = red_max32(tm);
        if (__any(tmax - m_run > 8.0f)) {
            float mnew = fmaxf(m_run, tmax);
            float alpha = exp2f(m_run - mnew);
            m_run = mnew;
            #pragma unroll
            for (int r = 0; r < 16; ++r) {
                o0[r] *= alpha; o1[r] *= alpha; lacc[r] *= alpha;
            }
        }
        float p0[16], p1[16], p2[16], p3[16];
        #pragma unroll
        for (int r = 0; r < 16; ++r) p0[r] = exp2f(s0[r] - m_run);
        #pragma unroll
        for (int r = 0; r < 16; ++r) p1[r] = exp2f(s1[r] - m_run);
        #pragma unroll
        for (int r = 0; r < 16; ++r) p2[r] = exp2f(s2[r] - m_run);
        #pragma unroll
        for (int r = 0; r < 16; ++r) p3[r] = exp2f(s3[r] - m_run);

        // ---- P -> bf16 A-frags: cvt_pk + permlane32_swap; pa[8] covers 128 j ----
        short8 pa[8];
        {
            const float* ps[4] = { p0, p1, p2, p3 };
            #pragma unroll
            for (int blk = 0; blk < 4; ++blk) {
                const float* p = ps[blk];
                #pragma unroll
                for (int jt = 0; jt < 2; ++jt) {
                    unsigned a0 = cvt_pk_bf16(p[jt * 8 + 0], p[jt * 8 + 1]);
                    unsigned a1 = cvt_pk_bf16(p[jt * 8 + 2], p[jt * 8 + 3]);
                    unsigned b0 = cvt_pk_bf16(p[jt * 8 + 4], p[jt * 8 + 5]);
                    unsigned b1 = cvt_pk_bf16(p[jt * 8 + 6], p[jt * 8 + 7]);
                    uint2 pr0 = permswap(a0, b0);
                    uint2 pr1 = permswap(a1, b1);
                    uint4 w;
                    w.x = pr0.x;
                    w.y = pr1.x;
                    w.z = pr0.y;
                    w.w = pr1.y;
                    pa[blk * 2 + jt] = __builtin_bit_cast(short8, w);
                }
            }
        }

        // ---- PV sub0 from pre-loaded regs; sub1 V reads issue between MFMAs ----
        __builtin_amdgcn_s_setprio(1);
        #pragma unroll
        for (int jt = 0; jt < 4; ++jt) {
            o0 = mfma32(vf[jt * 2], pa[jt], o0);
            o1 = mfma32(vf[jt * 2 + 1], pa[jt], o1);
            lacc = mfma32(ones, pa[jt], lacc);
        }
        #pragma unroll
        for (int jt = 0; jt < 4; ++jt) {
            int col = jt * 32 + hi * 16;
            short8 vg0 = *reinterpret_cast<const short8*>(Vc + 8192 + ((lam * 128 + col) ^ swz));
            o0 = mfma32(vg0, pa[4 + jt], o0);
            short8 vg1 = *reinterpret_cast<const short8*>(Vc + 8192 + (((lam + 32) * 128 + col) ^ swz));
            o1 = mfma32(vg1, pa[4 + jt], o1);
            lacc = mfma32(ones, pa[4 + jt], lacc);
        }
        __builtin_amdgcn_s_setprio(0);
    }

    float l_run = lacc[0];

    // ---- epilogue: O[q][d] = o[d-reg][q] / l ; write [B][T][H*64] ----
    float rinv = 1.0f / l_run;
    int b_ = bh >> 4, h_ = bh & 15;
    unsigned short* Orow = O + ((size_t)(b_ * 2048) + q) * 1024 + h_ * 64;
    #pragma unroll
    for (int rq = 0; rq < 4; ++rq) {
        ushort4 w0, w1;
        w0.x = f2bf(o0[rq * 4 + 0] * rinv);
        w0.y = f2bf(o0[rq * 4 + 1] * rinv);
        w0.z = f2bf(o0[rq * 4 + 2] * rinv);
        w0.w = f2bf(o0[rq * 4 + 3] * rinv);
        w1.x = f2bf(o1[rq * 4 + 0] * rinv);
        w1.y = f2bf(o1[rq * 4 + 1] * rinv);
        w1.z = f2bf(o1[rq * 4 + 2] * rinv);
        w1.w = f2bf(o1[rq * 4 + 3] * rinv);
        int d0 = rq * 8 + hi * 4;
        *reinterpret_cast<ushort4*>(Orow + d0) = w0;
        *reinterpret_cast<ushort4*>(Orow + 32 + d0) = w1;
    }
}

// ---------------- output GEMM (64x128 tile, grid 512 -> 2 blocks/CU) + bias, fp32 out ----------------
__global__ __launch_bounds__(512, 2) void out_gemm_kernel(
    const unsigned short* __restrict__ Aattn, const unsigned short* __restrict__ W,
    const float* __restrict__ bias, float* __restrict__ out) {
    __shared__ char smem[48 * 1024];    // A dbuf 16K + B dbuf 32K
    const int K = 1024, N = 1024;
    int flat = blockIdx.x;
    int swzb = (flat & 7) * 64 + (flat >> 3);
    int m0 = (swzb & 63) * 64, n0 = (swzb >> 6) * 128;
    f32x4 acc[2][2];
    #pragma unroll
    for (int i = 0; i < 2; ++i)
        #pragma unroll
        for (int j = 0; j < 2; ++j) acc[i][j] = zero4();

    gemm_mainloop<64, 128, 2, 4>(Aattn, W, K, m0, n0, smem, smem + 16384, acc);

    int tid = threadIdx.x;
    int wave = tid >> 6, lane = tid & 63;
    int wm = wave >> 2, wn = wave & 3;
    int g = lane >> 4, c = lane & 15;
    int mbase = m0 + wm * 32, nbase = n0 + wn * 32;
    #pragma unroll
    for (int mt = 0; mt < 2; ++mt)
        #pragma unroll
        for (int nt = 0; nt < 2; ++nt) {
            int n = nbase + nt * 16 + c;
            float bn = bias[n];
            #pragma unroll
            for (int r = 0; r < 4; ++r) {
                int m = mbase + mt * 16 + g * 4 + r;
                out[(size_t)m * N + n] = acc[mt][nt][r] + bn;
            }
        }
}

extern "C" void kernel_launch(void* const* d_in, const int* in_sizes, int n_in,
                              void* d_out, int out_size, void* d_ws, size_t ws_size,
                              hipStream_t stream) {
    (void)in_sizes; (void)n_in; (void)out_size; (void)ws_size;
    const float* x     = (const float*)d_in[0];
    const float* w_qkv = (const float*)d_in[1];
    const float* b_qkv = (const float*)d_in[2];
    const float* w_out = (const float*)d_in[3];
    const float* b_out = (const float*)d_in[4];
    float* out = (float*)d_out;

    const int B = 2, T = 2048, D = 1024;
    const int M = B * T;                 // 4096
    const size_t MB = 1024 * 1024;
    (void)D; (void)M;

    char* ws = (char*)d_ws;
    unsigned short* xb    = (unsigned short*)(ws);            // 8 MB  x bf16 [4096][1024]
    unsigned short* wqkvb = (unsigned short*)(ws + 8 * MB);   // 6 MB  w_qkv bf16
    unsigned short* woutb = (unsigned short*)(ws + 14 * MB);  // 2 MB  w_out bf16
    unsigned short* qb    = (unsigned short*)(ws + 16 * MB);  // 8 MB  q (pre-scaled) [32][2048][64]
    unsigned short* kb    = (unsigned short*)(ws + 24 * MB);  // 8 MB  k
    unsigned short* vtb   = (unsigned short*)(ws + 32 * MB);  // 8 MB  v^T [32][64][2048]
    unsigned short* attnb = (unsigned short*)(ws + 40 * MB);  // 8 MB  attn out [4096][1024]
    float2* tab           = (float2*)(ws + 48 * MB);          // 512 KB rope table

    prep_kernel<<<dim3((2097152 + 65536) / 256), dim3(256), 0, stream>>>(
        x, w_qkv, w_out, xb, wqkvb, woutb, tab);
    qkv_gemm_kernel<<<dim3(512), dim3(512), 0, stream>>>(xb, wqkvb, b_qkv, tab, qb, kb, vtb);
    attn_kernel<<<dim3(T / 128, B * 16), dim3(256), 0, stream>>>(qb, kb, vtb, attnb);
    out_gemm_kernel<<<dim3(512), dim3(512), 0, stream>>>(attnb, woutb, b_out, out);
}